// Round 14
// baseline (594.734 us; speedup 1.0000x reference)
//
#include <hip/hip_runtime.h>
#include <cstdint>

#define DEV static __device__ __forceinline__

typedef float f4v __attribute__((ext_vector_type(4)));
typedef short s8v __attribute__((ext_vector_type(8)));

// ---------- helpers ----------
DEV ushort f2bf(float f) {
  uint32_t u = __float_as_uint(f);
  uint32_t r = (u + 0x7FFFu + ((u >> 16) & 1u)) >> 16;   // RTNE
  return (ushort)r;
}
DEV float bf2f(ushort h) { return __uint_as_float(((uint32_t)h) << 16); }

DEV void lds_cp16(const void* g, void* l) {
  __builtin_amdgcn_global_load_lds((const __attribute__((address_space(1))) void*)g,
                                   (__attribute__((address_space(3))) void*)l, 16, 0, 0);
}

// ---------- constants ----------
#define BB 8
#define NN 1025
#define CC 1024
#define HH 16
#define DD 64
#define MM 25
#define KK 25
#define MROWS 8200          // B*N
#define SCALE 0.125f
#define GPITCH 28           // gateT row pitch (floats) -> 112B, 16B-aligned

// ---------- split x into bf16 hi/lo ----------
__global__ void split_x_kernel(const float* __restrict__ x, ushort* __restrict__ hi,
                               ushort* __restrict__ lo, int n4) {
  int i = blockIdx.x * 256 + threadIdx.x;
  if (i >= n4) return;
  float4 f = ((const float4*)x)[i];
  ushort4 h, l;
  h.x = f2bf(f.x); l.x = f2bf(f.x - bf2f(h.x));
  h.y = f2bf(f.y); l.y = f2bf(f.y - bf2f(h.y));
  h.z = f2bf(f.z); l.z = f2bf(f.z - bf2f(h.z));
  h.w = f2bf(f.w); l.w = f2bf(f.w - bf2f(h.w));
  ((ushort4*)hi)[i] = h;
  ((ushort4*)lo)[i] = l;
}

// ---------- transpose W[K][N] -> Wt[N][K] bf16 hi (+optional lo) ----------
__global__ void transpose_split_kernel(const float* __restrict__ W, ushort* __restrict__ hi,
                                       ushort* __restrict__ lo, int K, int N) {
  __shared__ float tile[32][33];
  int nb = blockIdx.x * 32, kb = blockIdx.y * 32;
  int tx = threadIdx.x, ty = threadIdx.y;      // 32x8
  for (int r = ty; r < 32; r += 8) tile[r][tx] = W[(size_t)(kb + r) * N + nb + tx];
  __syncthreads();
  for (int r = ty; r < 32; r += 8) {
    float f = tile[tx][r];                     // W[kb+tx][nb+r] -> Wt[nb+r][kb+tx]
    ushort h = f2bf(f);
    hi[(size_t)(nb + r) * K + kb + tx] = h;
    if (lo) lo[(size_t)(nb + r) * K + kb + tx] = f2bf(f - bf2f(h));
  }
}

// ---------- MFMA GEMM v3: 128x128 tile, double-buffered LDS, 2-phase pipeline (bf16x3) ----------
__global__ __launch_bounds__(256)
void gemm_dbuf_kernel(const ushort* __restrict__ Ah, const ushort* __restrict__ Al,
                      const ushort* __restrict__ Bh, const ushort* __restrict__ Bl,
                      float* __restrict__ C, const float* __restrict__ bias,
                      int M, int N, int K, int loN) {
  __shared__ ushort sm[32768];                 // 65536 B
  const int t = threadIdx.x;
  const int m0 = blockIdx.y * 128, n0 = blockIdx.x * 128;
  const bool three = (n0 < loN);
  const int lane = t & 63, wid = t >> 6;
  const int wy = wid >> 1, wx = wid & 1;       // 2x2 waves of 64x64
  const int lrow = lane & 15, lq = lane >> 4;
  const int slot = lq ^ ((lrow >> 1) & 3);     // fragment read swizzle

  f4v acc[4][4];
#pragma unroll
  for (int a = 0; a < 4; ++a)
#pragma unroll
    for (int b = 0; b < 4; ++b) acc[a][b] = (f4v)0.f;

  auto STAGE = [&](int p, int k0) {
    ushort* base = sm + p * 16384;
#pragma unroll
    for (int i = 0; i < 2; ++i) {
      int e = i * 256 + t;
      int row = e >> 2;
      int cgs = (e & 3) ^ ((e >> 3) & 3);      // staged k-group (XOR swizzle)
      int ebase = i * 256 + (t & 192);         // wave-uniform base
      size_t aoff = (size_t)min(m0 + row, M - 1) * K + k0 + cgs * 8;
      size_t boff = (size_t)(n0 + row) * K + k0 + cgs * 8;
      lds_cp16(Ah + aoff, base + (size_t)ebase * 8);
      lds_cp16(Bh + boff, base + 8192 + (size_t)ebase * 8);
      if (three) {
        lds_cp16(Al + aoff, base + 4096 + (size_t)ebase * 8);
        lds_cp16(Bl + boff, base + 12288 + (size_t)ebase * 8);
      }
    }
  };

  STAGE(0, 0);
  __syncthreads();
  int cur = 0;
  for (int k0 = 0; k0 < K; k0 += 32) {
    if (k0 + 32 < K) STAGE(cur ^ 1, k0 + 32);  // issue next tile (overlaps compute below)
    const ushort* sAh = sm + cur * 16384;
    const ushort* sAl = sAh + 4096;
    const ushort* sBh = sAh + 8192;
    const ushort* sBl = sAh + 12288;
    s8v fa[4], fb[4];
#pragma unroll
    for (int u = 0; u < 4; ++u) {
      fa[u] = *(const s8v*)(sAh + (((wy * 64 + u * 16 + lrow) * 4 + slot) * 8));
      fb[u] = *(const s8v*)(sBh + (((wx * 64 + u * 16 + lrow) * 4 + slot) * 8));
    }
#pragma unroll
    for (int mt = 0; mt < 4; ++mt)
#pragma unroll
      for (int nt = 0; nt < 4; ++nt)
        acc[mt][nt] = __builtin_amdgcn_mfma_f32_16x16x32_bf16(fa[mt], fb[nt], acc[mt][nt], 0, 0, 0);
    if (three) {
      s8v la[4], lb[4];
#pragma unroll
      for (int u = 0; u < 4; ++u) {
        la[u] = *(const s8v*)(sAl + (((wy * 64 + u * 16 + lrow) * 4 + slot) * 8));
        lb[u] = *(const s8v*)(sBl + (((wx * 64 + u * 16 + lrow) * 4 + slot) * 8));
      }
#pragma unroll
      for (int mt = 0; mt < 4; ++mt)
#pragma unroll
        for (int nt = 0; nt < 4; ++nt) {
          acc[mt][nt] = __builtin_amdgcn_mfma_f32_16x16x32_bf16(fa[mt], lb[nt], acc[mt][nt], 0, 0, 0);
          acc[mt][nt] = __builtin_amdgcn_mfma_f32_16x16x32_bf16(la[mt], fb[nt], acc[mt][nt], 0, 0, 0);
        }
    }
    __syncthreads();   // drains next-tile loads + fences read-before-overwrite
    cur ^= 1;
  }
  // epilogue: C/D layout col=lane&15, row=(lane>>4)*4+i  [m89/m91-verified]
#pragma unroll
  for (int mt = 0; mt < 4; ++mt) {
#pragma unroll
    for (int i = 0; i < 4; ++i) {
      int r = m0 + wy * 64 + mt * 16 + lq * 4 + i;
      if (r < M) {
#pragma unroll
        for (int nt = 0; nt < 4; ++nt) {
          int c = n0 + wx * 64 + nt * 16 + lrow;
          float v = acc[mt][nt][i];
          if (bias) v += bias[c];
          C[(size_t)r * N + c] = v;
        }
      }
    }
  }
}

// ---------- MFMA GEMM plain: 128x128 dbuf, NO hi/lo split -> 32KB LDS, 5 blocks/CU ----------
__global__ __launch_bounds__(256)
void gemm_dbuf_plain_kernel(const ushort* __restrict__ Ah, const ushort* __restrict__ Bh,
                            float* __restrict__ C, const float* __restrict__ bias,
                            int M, int N, int K) {
  __shared__ ushort sm[16384];                 // 32768 B: 2 bufs x (A 8KB | B 8KB)
  const int t = threadIdx.x;
  const int m0 = blockIdx.y * 128, n0 = blockIdx.x * 128;
  const int lane = t & 63, wid = t >> 6;
  const int wy = wid >> 1, wx = wid & 1;
  const int lrow = lane & 15, lq = lane >> 4;
  const int slot = lq ^ ((lrow >> 1) & 3);

  f4v acc[4][4];
#pragma unroll
  for (int a = 0; a < 4; ++a)
#pragma unroll
    for (int b = 0; b < 4; ++b) acc[a][b] = (f4v)0.f;

  auto STAGE = [&](int p, int k0) {
    ushort* base = sm + p * 8192;
#pragma unroll
    for (int i = 0; i < 2; ++i) {
      int e = i * 256 + t;
      int row = e >> 2;
      int cgs = (e & 3) ^ ((e >> 3) & 3);
      int ebase = i * 256 + (t & 192);
      size_t aoff = (size_t)min(m0 + row, M - 1) * K + k0 + cgs * 8;
      size_t boff = (size_t)(n0 + row) * K + k0 + cgs * 8;
      lds_cp16(Ah + aoff, base + (size_t)ebase * 8);
      lds_cp16(Bh + boff, base + 4096 + (size_t)ebase * 8);
    }
  };

  STAGE(0, 0);
  __syncthreads();
  int cur = 0;
  for (int k0 = 0; k0 < K; k0 += 32) {
    if (k0 + 32 < K) STAGE(cur ^ 1, k0 + 32);
    const ushort* sAh = sm + cur * 8192;
    const ushort* sBh = sAh + 4096;
    s8v fa[4], fb[4];
#pragma unroll
    for (int u = 0; u < 4; ++u) {
      fa[u] = *(const s8v*)(sAh + (((wy * 64 + u * 16 + lrow) * 4 + slot) * 8));
      fb[u] = *(const s8v*)(sBh + (((wx * 64 + u * 16 + lrow) * 4 + slot) * 8));
    }
#pragma unroll
    for (int mt = 0; mt < 4; ++mt)
#pragma unroll
      for (int nt = 0; nt < 4; ++nt)
        acc[mt][nt] = __builtin_amdgcn_mfma_f32_16x16x32_bf16(fa[mt], fb[nt], acc[mt][nt], 0, 0, 0);
    __syncthreads();
    cur ^= 1;
  }
#pragma unroll
  for (int mt = 0; mt < 4; ++mt) {
#pragma unroll
    for (int i = 0; i < 4; ++i) {
      int r = m0 + wy * 64 + mt * 16 + lq * 4 + i;
      if (r < M) {
#pragma unroll
        for (int nt = 0; nt < 4; ++nt) {
          int c = n0 + wx * 64 + nt * 16 + lrow;
          float v = acc[mt][nt][i];
          if (bias) v += bias[c];
          C[(size_t)r * N + c] = v;
        }
      }
    }
  }
}

// ---------- adaptive-pool router v2: grid (200, 4) x 256 threads -> all CUs busy ----------
__global__ __launch_bounds__(256)
void pool_router2_kernel(const float* __restrict__ qkv, float* __restrict__ router) {
  int bm = blockIdx.x;                 // b*25 + m
  int b = bm / 25, m = bm % 25;
  int p = m / 5, q = m % 5;
  int sp = (p * 32) / 5, ep = ((p + 1) * 32 + 4) / 5;
  int sq = (q * 32) / 5, eq = ((q + 1) * 32 + 4) / 5;
  float inv = 1.0f / (float)((ep - sp) * (eq - sq));
  int c = blockIdx.y * 256 + threadIdx.x;
  float s0 = 0.f;
  for (int hh = sp; hh < ep; ++hh)
    for (int ww = sq; ww < eq; ++ww)
      s0 += qkv[(size_t)(b * NN + hh * 32 + ww) * 3072 + c];
  router[(size_t)bm * 1024 + c] = s0 * inv;
}

// ---------- fused router logits + coalesced rlogT/gateT + argmax assign ----------
__global__ __launch_bounds__(256)
void rg_fused_kernel(const float* __restrict__ qkv, const float* __restrict__ router,
                     float* __restrict__ rlog, float* __restrict__ rlogT,
                     float* __restrict__ gateT,
                     int* __restrict__ cnt, int* __restrict__ qlist) {
  __shared__ float sQ[64 * 68];        // pitch 68 -> b128 reads conflict-free
  __shared__ float sK[64 * 68];
  __shared__ float sR[25 * 64];
  __shared__ float sG[64 * 27];        // gate tile, odd-ish pitch
  int bh = blockIdx.x, s = blockIdx.y;
  int b = bh >> 4, h = bh & 15;
  int base = s * 64, seglen = min(64, NN - base);
  int t = threadIdx.x;
  for (int e = t; e < 400; e += 256) {           // r: 25 rows x 16 float4
    int m = e >> 4, c4 = e & 15;
    *(float4*)&sR[m * 64 + c4 * 4] =
        *(const float4*)(router + (size_t)(b * 25 + m) * 1024 + h * 64 + c4 * 4);
  }
  for (int e = t; e < seglen * 16; e += 256) {   // q,k tiles coalesced
    int row = e >> 4, c4 = e & 15;
    const float* src = qkv + (size_t)(b * NN + base + row) * 3072 + h * 64 + c4 * 4;
    *(float4*)&sQ[row * 68 + c4 * 4] = *(const float4*)(src);
    *(float4*)&sK[row * 68 + c4 * 4] = *(const float4*)(src + 1024);
  }
  __syncthreads();
  int nl = t & 63, w = t >> 6;
  float kl[7];                         // k-logits, statically indexed (rule #20)
#pragma unroll
  for (int j = 0; j < 7; ++j) kl[j] = 0.f;
  if (nl < seglen) {
    float4 rowreg[16];
#pragma unroll
    for (int c4 = 0; c4 < 16; ++c4) rowreg[c4] = *(const float4*)&sQ[nl * 68 + c4 * 4];
    for (int m = w; m < 25; m += 4) {
      const float* rp = &sR[m * 64];
      float a = 0.f;
#pragma unroll
      for (int c4 = 0; c4 < 16; ++c4) {
        float4 r4 = *(const float4*)(rp + c4 * 4);        // broadcast within wave
        a += rowreg[c4].x * r4.x + rowreg[c4].y * r4.y +
             rowreg[c4].z * r4.z + rowreg[c4].w * r4.w;
      }
      sG[nl * 27 + m] = a;
    }
#pragma unroll
    for (int c4 = 0; c4 < 16; ++c4) rowreg[c4] = *(const float4*)&sK[nl * 68 + c4 * 4];
#pragma unroll
    for (int j = 0; j < 7; ++j) {
      int m = w + 4 * j;
      if (m < 25) {
        const float* rp = &sR[m * 64];
        float a = 0.f;
#pragma unroll
        for (int c4 = 0; c4 < 16; ++c4) {
          float4 r4 = *(const float4*)(rp + c4 * 4);
          a += rowreg[c4].x * r4.x + rowreg[c4].y * r4.y +
               rowreg[c4].z * r4.z + rowreg[c4].w * r4.w;
        }
        rlog[(size_t)(bh * 25 + m) * NN + base + nl] = a;   // coalesced per m
        kl[j] = a;
      }
    }
  }
  __syncthreads();                     // A: all sQ reads complete -> safe to reuse
  float* sT = sQ;                      // [64][26] scratch for rlogT transpose
  if (nl < seglen) {
#pragma unroll
    for (int j = 0; j < 7; ++j) {
      int m = w + 4 * j;
      if (m < 25) sT[nl * 26 + m] = kl[j];
    }
  }
  __syncthreads();                     // B: sT complete (sG stable since before A)
  {
    // rlogT [seglen x 25] target region is exactly linear -> fully coalesced dwords
    float* dst = rlogT + (size_t)(bh * NN + base) * 25;
    for (int i = t; i < seglen * 25; i += 256) {
      int row = i / 25, m = i - row * 25;
      dst[i] = sT[row * 26 + m];
    }
  }
  {
    // gateT [seglen x GPITCH] contiguous dump from sG (padding lanes write 0, never read)
    float* dst = gateT + (size_t)(bh * NN + base) * GPITCH;
    for (int i = t; i < seglen * GPITCH; i += 256) {
      int row = i / GPITCH, m = i - row * GPITCH;
      dst[i] = (m < 25) ? sG[row * 27 + m] : 0.f;
    }
  }
  if (t < seglen) {
    const float* gp = &sG[t * 27];
    float best = -INFINITY; int bi = 0;
#pragma unroll
    for (int m = 0; m < 25; ++m) {
      float v = gp[m];
      if (v > best) { best = v; bi = m; }      // strict > : first-max, matches jnp.argmax
    }
    int pos = atomicAdd(&cnt[bh * 25 + bi], 1);
    qlist[(bh * 25 + bi) * NN + pos] = base + t;
  }
}

// ---------- top-25 of each rlog row + softmax row stats (one wave per row) ----------
__global__ void topk2_kernel(const float* __restrict__ rlog, int* __restrict__ topk,
                             float* __restrict__ rowMax, float* __restrict__ rowRcp) {
  int row = blockIdx.x;                // (b*16+h)*25+m
  int l = threadIdx.x;                 // 0..63
  const float* src = rlog + (size_t)row * NN;
  float vals[17];
#pragma unroll
  for (int i = 0; i < 17; ++i) {
    int n = l + i * 64;
    vals[i] = (n < NN) ? src[n] : -INFINITY;
  }
  {
    float mx = vals[0];
#pragma unroll
    for (int i = 1; i < 17; ++i) mx = fmaxf(mx, vals[i]);
#pragma unroll
    for (int off = 32; off; off >>= 1) mx = fmaxf(mx, __shfl_xor(mx, off));
    float mxs = mx * SCALE;
    float sum = 0.f;
#pragma unroll
    for (int i = 0; i < 17; ++i) sum += __expf(vals[i] * SCALE - mxs);  // exp(-inf)=0
#pragma unroll
    for (int off = 32; off; off >>= 1) sum += __shfl_xor(sum, off);
    if (l == 0) { rowMax[row] = mxs; rowRcp[row] = 1.0f / sum; }
  }
  int* out = topk + row * 25;
  for (int r = 0; r < 25; ++r) {
    float best = vals[0]; int bi = 0;
#pragma unroll
    for (int i = 1; i < 17; ++i)
      if (vals[i] > best) { best = vals[i]; bi = i; }
    int bn = l + bi * 64;
#pragma unroll
    for (int off = 32; off; off >>= 1) {
      float ov = __shfl_down(best, off);
      int on = __shfl_down(bn, off);
      if (ov > best || (ov == best && on < bn)) { best = ov; bn = on; }
    }
    bn = __shfl(bn, 0);
    if (l == 0) out[r] = bn;
    if ((bn & 63) == l) vals[bn >> 6] = -INFINITY;
  }
}

// ---------- agent value v7: V read ONCE; per-n contiguous rlogT weights; LDS wave-reduce ----------
__global__ __launch_bounds__(256)
void agent_value7_kernel(const float* __restrict__ qkv, const float* __restrict__ rlogT,
                         const float* __restrict__ rowMax, const float* __restrict__ rowRcp,
                         float* __restrict__ av) {
  __shared__ float red[4][25][64];     // 25.6 KB
  int bh = blockIdx.x, sl = blockIdx.y;
  int w = threadIdx.x >> 6, l = threadIdx.x & 63;
  int b = bh >> 4, h = bh & 15;
  int n0 = (sl * 4 + w) * 32;
  int n1 = (sl == 7 && w == 3) ? NN : n0 + 32;
  float mxs[25];
#pragma unroll
  for (int m = 0; m < 25; ++m) mxs[m] = rowMax[bh * 25 + m];
  const float* vb = qkv + (size_t)b * NN * 3072 + 2048 + h * 64 + l;
  const float* rT = rlogT + (size_t)bh * NN * 25;
  float acc[25];
#pragma unroll
  for (int m = 0; m < 25; ++m) acc[m] = 0.f;
  for (int n = n0; n < n1; ++n) {
    float v = vb[(size_t)n * 3072];              // coalesced 256B row, read once
    const float* r = rT + (size_t)n * 25;        // wave-uniform contiguous 25 floats
#pragma unroll
    for (int m = 0; m < 25; ++m)
      acc[m] += __expf(r[m] * SCALE - mxs[m]) * v;
  }
#pragma unroll
  for (int m = 0; m < 25; ++m) red[w][m][l] = acc[m];
  __syncthreads();
  for (int i = threadIdx.x; i < 1600; i += 256) {
    int m = i >> 6, ll = i & 63;
    float s = red[0][m][ll] + red[1][m][ll] + red[2][m][ll] + red[3][m][ll];
    atomicAdd(&av[((size_t)bh * 25 + m) * 64 + ll], s * rowRcp[bh * 25 + m]);
  }
}

// ---------- mixed attention v10: early-issue q+gate loads (latency hides under staging) ----------
__global__ __launch_bounds__(64)
void mixed_attn10_kernel(const float* __restrict__ qkv, const float* __restrict__ gateT,
                         const int* __restrict__ topk, const float* __restrict__ av,
                         const int* __restrict__ cnt, const int* __restrict__ qlist,
                         ushort* __restrict__ attn) {
  __shared__ float sK[25 * 64];
  __shared__ float sV[25 * 64];
  __shared__ float sA[25 * 64];
  int e = blockIdx.x, bh = blockIdx.y;
  int c0 = blockIdx.z * 64;
  int ce = cnt[bh * 25 + e];
  if (c0 >= ce) return;
  int b = bh >> 4, h = bh & 15;
  int l = threadIdx.x;                 // 64 threads = 1 wave
  const int* tkp = topk + bh * 625 + e * 25;
  const float* qb = qkv + (size_t)b * NN * 3072 + h * 64;
  const int* ql = qlist + (bh * 25 + e) * NN;

  // ---- early-issue per-lane loads: q row (scattered) + gate row; in flight during staging ----
  int qi = c0 + l;
  bool act = qi < ce;
  int n = ql[act ? qi : c0];
  const float* qr = qb + (size_t)n * 3072;
  float4 q4[16];
#pragma unroll
  for (int d4 = 0; d4 < 16; ++d4) q4[d4] = *(const float4*)(qr + d4 * 4);
  const float* gr = gateT + ((size_t)bh * NN + n) * GPITCH;
  float4 gv0 = *(const float4*)(gr);
  float4 gv1 = *(const float4*)(gr + 4);
  float4 gv2 = *(const float4*)(gr + 8);
  float4 gv3 = *(const float4*)(gr + 12);
  float4 gv4 = *(const float4*)(gr + 16);
  float4 gv5 = *(const float4*)(gr + 20);
  float g24 = gr[24];

  // ---- cooperative stage (coalesced): 25 K rows, 25 V rows, 25 AV rows ----
  for (int i = l; i < 400; i += 64) {
    int row = i >> 4, c4 = (i & 15) * 4;
    const float* src = qb + (size_t)tkp[row] * 3072 + 1024 + c4;
    *(float4*)&sK[row * 64 + c4] = *(const float4*)(src);
    *(float4*)&sV[row * 64 + c4] = *(const float4*)(src + 1024);
  }
  {
    const float* avb = av + (size_t)bh * 25 * 64;
    for (int i = l; i < 400; i += 64)
      *(float4*)&sA[i * 4] = *(const float4*)(avb + i * 4);
  }
  __syncthreads();   // drains staging AND the early-issued q4/gate loads together

  // ---- pass 1: all 50 logits into registers ----
  float myW[50];
  myW[0] = gv0.x; myW[1] = gv0.y; myW[2] = gv0.z; myW[3] = gv0.w;
  myW[4] = gv1.x; myW[5] = gv1.y; myW[6] = gv1.z; myW[7] = gv1.w;
  myW[8] = gv2.x; myW[9] = gv2.y; myW[10] = gv2.z; myW[11] = gv2.w;
  myW[12] = gv3.x; myW[13] = gv3.y; myW[14] = gv3.z; myW[15] = gv3.w;
  myW[16] = gv4.x; myW[17] = gv4.y; myW[18] = gv4.z; myW[19] = gv4.w;
  myW[20] = gv5.x; myW[21] = gv5.y; myW[22] = gv5.z; myW[23] = gv5.w;
  myW[24] = g24;
#pragma unroll
  for (int m = 0; m < 25; ++m) myW[m] *= SCALE;
#pragma unroll
  for (int j = 0; j < 25; ++j) {
    const float4* kr = (const float4*)&sK[j * 64];
    float a = 0.f;
#pragma unroll
    for (int d4 = 0; d4 < 16; ++d4) {
      float4 k4 = kr[d4];
      a += q4[d4].x * k4.x + q4[d4].y * k4.y + q4[d4].z * k4.z + q4[d4].w * k4.w;
    }
    myW[25 + j] = a * SCALE;
  }
  // ---- softmax over 50 (unnormalized exps; normalize at store) ----
  float mx = myW[0];
#pragma unroll
  for (int i = 1; i < 50; ++i) mx = fmaxf(mx, myW[i]);
  float tot = 0.f;
#pragma unroll
  for (int i = 0; i < 50; ++i) { float w = __expf(myW[i] - mx); myW[i] = w; tot += w; }
  float rcp = 1.0f / tot;

  // ---- pass 2: output accumulate from LDS ----
  float4 o[16];
#pragma unroll
  for (int d4 = 0; d4 < 16; ++d4) o[d4] = make_float4(0.f, 0.f, 0.f, 0.f);
#pragma unroll
  for (int m = 0; m < 25; ++m) {
    const float4* src = (const float4*)&sA[m * 64];
    float wv = myW[m];
#pragma unroll
    for (int d4 = 0; d4 < 16; ++d4) {
      float4 a4 = src[d4];
      o[d4].x += wv * a4.x; o[d4].y += wv * a4.y;
      o[d4].z += wv * a4.z; o[d4].w += wv * a4.w;
    }
  }
#pragma unroll
  for (int j = 0; j < 25; ++j) {
    const float4* src = (const float4*)&sV[j * 64];
    float wv = myW[25 + j];
#pragma unroll
    for (int d4 = 0; d4 < 16; ++d4) {
      float4 a4 = src[d4];
      o[d4].x += wv * a4.x; o[d4].y += wv * a4.y;
      o[d4].z += wv * a4.z; o[d4].w += wv * a4.w;
    }
  }
  if (act) {
    ushort* orow = attn + (size_t)(b * NN + n) * 1024 + h * 64;
#pragma unroll
    for (int d4 = 0; d4 < 16; ++d4) {
      ushort4 u;
      u.x = f2bf(o[d4].x * rcp); u.y = f2bf(o[d4].y * rcp);
      u.z = f2bf(o[d4].z * rcp); u.w = f2bf(o[d4].w * rcp);
      *(ushort4*)(orow + d4 * 4) = u;
    }
  }
}

// ---------- launch ----------
extern "C" void kernel_launch(void* const* d_in, const int* in_sizes, int n_in,
                              void* d_out, int out_size, void* d_ws, size_t ws_size,
                              hipStream_t stream) {
  const float* x = (const float*)d_in[0];
  const float* Wqkv = (const float*)d_in[1];
  const float* Wproj = (const float*)d_in[2];
  const float* bproj = (const float*)d_in[3];

  char* ws = (char*)d_ws;
  size_t off = 0;
  float* qkv = (float*)(ws + off);      off += (size_t)MROWS * 3072 * 4;    // 100,761,600
  ushort* xh = (ushort*)(ws + off);     off += (size_t)MROWS * 1024 * 2;    // 16,793,600
  ushort* xl = (ushort*)(ws + off);     off += (size_t)MROWS * 1024 * 2;
  ushort* Wth = (ushort*)(ws + off);    off += (size_t)3072 * 1024 * 2;     // 6,291,456
  ushort* Wtl = (ushort*)(ws + off);    off += (size_t)3072 * 1024 * 2;
  ushort* WpT = (ushort*)(ws + off);    off += (size_t)1024 * 1024 * 2;     // 2,097,152
  float* router = (float*)(ws + off);   off += (size_t)BB * 25 * 1024 * 4;  // 819,200
  float* rlog = (float*)(ws + off);     off += (size_t)BB * HH * 25 * NN * 4; // 13,120,000
  float* rlogT = (float*)(ws + off);    off += (size_t)BB * HH * NN * 25 * 4; // 13,120,000
  int* topk = (int*)(ws + off);         off += (size_t)BB * HH * 25 * 25 * 4; // 320,000
  float* av = (float*)(ws + off);       off += (size_t)BB * HH * 25 * 64 * 4; // 819,200
  ushort* attn = (ushort*)(ws + off);   off += (size_t)MROWS * 1024 * 2;
  float* rowMax = (float*)(ws + off);   off += (size_t)BB * HH * 25 * 4;    // 12,800
  float* rowRcp = (float*)(ws + off);   off += (size_t)BB * HH * 25 * 4;

  // xh/xl are dead after the qkv GEMM -> reuse for routing metadata
  float* gateT = (float*)xh;                               // 128*1025*28*4 = 14,694,400 B
  int* cnt = (int*)((char*)xh + 14694400);                 // 12,800 B (total <= 16,793,600)
  int* qlist = (int*)xl;                                   // 13,120,000 B

  split_x_kernel<<<8200, 256, 0, stream>>>(x, xh, xl, 2099200);
  transpose_split_kernel<<<dim3(96, 32), dim3(32, 8), 0, stream>>>(Wqkv, Wth, Wtl, 1024, 3072);
  transpose_split_kernel<<<dim3(32, 32), dim3(32, 8), 0, stream>>>(Wproj, WpT, nullptr, 1024, 1024);
  // qkv = x @ Wqkv : bf16x3 for q,k columns (<2048), plain bf16 for v columns
  gemm_dbuf_kernel<<<dim3(24, 65), 256, 0, stream>>>(xh, xl, Wth, Wtl, qkv, nullptr,
                                                     MROWS, 3072, 1024, 2048);
  // --- probe: pool_router2 is pure; run 3x (delta = 2x its cost) ---
  pool_router2_kernel<<<dim3(BB * 25, 4), 256, 0, stream>>>(qkv, router);
  pool_router2_kernel<<<dim3(BB * 25, 4), 256, 0, stream>>>(qkv, router);
  pool_router2_kernel<<<dim3(BB * 25, 4), 256, 0, stream>>>(qkv, router);
  hipMemsetAsync(cnt, 0, 3200 * 4, stream);
  hipMemsetAsync(av, 0, (size_t)BB * HH * 25 * 64 * 4, stream);
  rg_fused_kernel<<<dim3(128, 17), 256, 0, stream>>>(qkv, router, rlog, rlogT, gateT, cnt, qlist);
  // --- probe: topk2 is pure; run 3x (delta = 2x its cost) ---
  topk2_kernel<<<BB * HH * 25, 64, 0, stream>>>(rlog, topk, rowMax, rowRcp);
  topk2_kernel<<<BB * HH * 25, 64, 0, stream>>>(rlog, topk, rowMax, rowRcp);
  topk2_kernel<<<BB * HH * 25, 64, 0, stream>>>(rlog, topk, rowMax, rowRcp);
  agent_value7_kernel<<<dim3(128, 8), 256, 0, stream>>>(qkv, rlogT, rowMax, rowRcp, av);
  mixed_attn10_kernel<<<dim3(25, 128, 17), 64, 0, stream>>>(qkv, gateT, topk, av, cnt, qlist, attn);
  // out = attn @ Wproj + bproj : plain bf16 (32KB-LDS kernel -> 5 blocks/CU, no tail round)
  gemm_dbuf_plain_kernel<<<dim3(8, 65), 256, 0, stream>>>(attn, WpT, (float*)d_out, bproj,
                                                          MROWS, 1024, 1024);
}

// Round 15
// 580.708 us; speedup vs baseline: 1.0242x; 1.0242x over previous
//
#include <hip/hip_runtime.h>
#include <cstdint>

#define DEV static __device__ __forceinline__

typedef float f4v __attribute__((ext_vector_type(4)));
typedef short s8v __attribute__((ext_vector_type(8)));

// ---------- helpers ----------
DEV ushort f2bf(float f) {
  uint32_t u = __float_as_uint(f);
  uint32_t r = (u + 0x7FFFu + ((u >> 16) & 1u)) >> 16;   // RTNE
  return (ushort)r;
}
DEV float bf2f(ushort h) { return __uint_as_float(((uint32_t)h) << 16); }

DEV void lds_cp16(const void* g, void* l) {
  __builtin_amdgcn_global_load_lds((const __attribute__((address_space(1))) void*)g,
                                   (__attribute__((address_space(3))) void*)l, 16, 0, 0);
}

// ---------- constants ----------
#define BB 8
#define NN 1025
#define CC 1024
#define HH 16
#define DD 64
#define MM 25
#define KK 25
#define MROWS 8200          // B*N
#define SCALE 0.125f
#define GPITCH 28           // gateT row pitch (floats) -> 112B, 16B-aligned

// ---------- split x into bf16 hi/lo ----------
__global__ void split_x_kernel(const float* __restrict__ x, ushort* __restrict__ hi,
                               ushort* __restrict__ lo, int n4) {
  int i = blockIdx.x * 256 + threadIdx.x;
  if (i >= n4) return;
  float4 f = ((const float4*)x)[i];
  ushort4 h, l;
  h.x = f2bf(f.x); l.x = f2bf(f.x - bf2f(h.x));
  h.y = f2bf(f.y); l.y = f2bf(f.y - bf2f(h.y));
  h.z = f2bf(f.z); l.z = f2bf(f.z - bf2f(h.z));
  h.w = f2bf(f.w); l.w = f2bf(f.w - bf2f(h.w));
  ((ushort4*)hi)[i] = h;
  ((ushort4*)lo)[i] = l;
}

// ---------- transpose W[K][N] -> Wt[N][K] bf16 hi (+optional lo) ----------
__global__ void transpose_split_kernel(const float* __restrict__ W, ushort* __restrict__ hi,
                                       ushort* __restrict__ lo, int K, int N) {
  __shared__ float tile[32][33];
  int nb = blockIdx.x * 32, kb = blockIdx.y * 32;
  int tx = threadIdx.x, ty = threadIdx.y;      // 32x8
  for (int r = ty; r < 32; r += 8) tile[r][tx] = W[(size_t)(kb + r) * N + nb + tx];
  __syncthreads();
  for (int r = ty; r < 32; r += 8) {
    float f = tile[tx][r];                     // W[kb+tx][nb+r] -> Wt[nb+r][kb+tx]
    ushort h = f2bf(f);
    hi[(size_t)(nb + r) * K + kb + tx] = h;
    if (lo) lo[(size_t)(nb + r) * K + kb + tx] = f2bf(f - bf2f(h));
  }
}

// ---------- MFMA GEMM v3: 128x128 tile, double-buffered LDS, 2-phase pipeline (bf16x3) ----------
__global__ __launch_bounds__(256)
void gemm_dbuf_kernel(const ushort* __restrict__ Ah, const ushort* __restrict__ Al,
                      const ushort* __restrict__ Bh, const ushort* __restrict__ Bl,
                      float* __restrict__ C, const float* __restrict__ bias,
                      int M, int N, int K, int loN) {
  __shared__ ushort sm[32768];                 // 65536 B
  const int t = threadIdx.x;
  const int m0 = blockIdx.y * 128, n0 = blockIdx.x * 128;
  const bool three = (n0 < loN);
  const int lane = t & 63, wid = t >> 6;
  const int wy = wid >> 1, wx = wid & 1;       // 2x2 waves of 64x64
  const int lrow = lane & 15, lq = lane >> 4;
  const int slot = lq ^ ((lrow >> 1) & 3);     // fragment read swizzle

  f4v acc[4][4];
#pragma unroll
  for (int a = 0; a < 4; ++a)
#pragma unroll
    for (int b = 0; b < 4; ++b) acc[a][b] = (f4v)0.f;

  auto STAGE = [&](int p, int k0) {
    ushort* base = sm + p * 16384;
#pragma unroll
    for (int i = 0; i < 2; ++i) {
      int e = i * 256 + t;
      int row = e >> 2;
      int cgs = (e & 3) ^ ((e >> 3) & 3);      // staged k-group (XOR swizzle)
      int ebase = i * 256 + (t & 192);         // wave-uniform base
      size_t aoff = (size_t)min(m0 + row, M - 1) * K + k0 + cgs * 8;
      size_t boff = (size_t)(n0 + row) * K + k0 + cgs * 8;
      lds_cp16(Ah + aoff, base + (size_t)ebase * 8);
      lds_cp16(Bh + boff, base + 8192 + (size_t)ebase * 8);
      if (three) {
        lds_cp16(Al + aoff, base + 4096 + (size_t)ebase * 8);
        lds_cp16(Bl + boff, base + 12288 + (size_t)ebase * 8);
      }
    }
  };

  STAGE(0, 0);
  __syncthreads();
  int cur = 0;
  for (int k0 = 0; k0 < K; k0 += 32) {
    if (k0 + 32 < K) STAGE(cur ^ 1, k0 + 32);  // issue next tile (overlaps compute below)
    const ushort* sAh = sm + cur * 16384;
    const ushort* sAl = sAh + 4096;
    const ushort* sBh = sAh + 8192;
    const ushort* sBl = sAh + 12288;
    s8v fa[4], fb[4];
#pragma unroll
    for (int u = 0; u < 4; ++u) {
      fa[u] = *(const s8v*)(sAh + (((wy * 64 + u * 16 + lrow) * 4 + slot) * 8));
      fb[u] = *(const s8v*)(sBh + (((wx * 64 + u * 16 + lrow) * 4 + slot) * 8));
    }
#pragma unroll
    for (int mt = 0; mt < 4; ++mt)
#pragma unroll
      for (int nt = 0; nt < 4; ++nt)
        acc[mt][nt] = __builtin_amdgcn_mfma_f32_16x16x32_bf16(fa[mt], fb[nt], acc[mt][nt], 0, 0, 0);
    if (three) {
      s8v la[4], lb[4];
#pragma unroll
      for (int u = 0; u < 4; ++u) {
        la[u] = *(const s8v*)(sAl + (((wy * 64 + u * 16 + lrow) * 4 + slot) * 8));
        lb[u] = *(const s8v*)(sBl + (((wx * 64 + u * 16 + lrow) * 4 + slot) * 8));
      }
#pragma unroll
      for (int mt = 0; mt < 4; ++mt)
#pragma unroll
        for (int nt = 0; nt < 4; ++nt) {
          acc[mt][nt] = __builtin_amdgcn_mfma_f32_16x16x32_bf16(fa[mt], lb[nt], acc[mt][nt], 0, 0, 0);
          acc[mt][nt] = __builtin_amdgcn_mfma_f32_16x16x32_bf16(la[mt], fb[nt], acc[mt][nt], 0, 0, 0);
        }
    }
    __syncthreads();   // drains next-tile loads + fences read-before-overwrite
    cur ^= 1;
  }
  // epilogue: C/D layout col=lane&15, row=(lane>>4)*4+i  [m89/m91-verified]
#pragma unroll
  for (int mt = 0; mt < 4; ++mt) {
#pragma unroll
    for (int i = 0; i < 4; ++i) {
      int r = m0 + wy * 64 + mt * 16 + lq * 4 + i;
      if (r < M) {
#pragma unroll
        for (int nt = 0; nt < 4; ++nt) {
          int c = n0 + wx * 64 + nt * 16 + lrow;
          float v = acc[mt][nt][i];
          if (bias) v += bias[c];
          C[(size_t)r * N + c] = v;
        }
      }
    }
  }
}

// ---------- MFMA GEMM plain: 128x128 dbuf, NO hi/lo split -> 32KB LDS, 5 blocks/CU ----------
__global__ __launch_bounds__(256)
void gemm_dbuf_plain_kernel(const ushort* __restrict__ Ah, const ushort* __restrict__ Bh,
                            float* __restrict__ C, const float* __restrict__ bias,
                            int M, int N, int K) {
  __shared__ ushort sm[16384];                 // 32768 B: 2 bufs x (A 8KB | B 8KB)
  const int t = threadIdx.x;
  const int m0 = blockIdx.y * 128, n0 = blockIdx.x * 128;
  const int lane = t & 63, wid = t >> 6;
  const int wy = wid >> 1, wx = wid & 1;
  const int lrow = lane & 15, lq = lane >> 4;
  const int slot = lq ^ ((lrow >> 1) & 3);

  f4v acc[4][4];
#pragma unroll
  for (int a = 0; a < 4; ++a)
#pragma unroll
    for (int b = 0; b < 4; ++b) acc[a][b] = (f4v)0.f;

  auto STAGE = [&](int p, int k0) {
    ushort* base = sm + p * 8192;
#pragma unroll
    for (int i = 0; i < 2; ++i) {
      int e = i * 256 + t;
      int row = e >> 2;
      int cgs = (e & 3) ^ ((e >> 3) & 3);
      int ebase = i * 256 + (t & 192);
      size_t aoff = (size_t)min(m0 + row, M - 1) * K + k0 + cgs * 8;
      size_t boff = (size_t)(n0 + row) * K + k0 + cgs * 8;
      lds_cp16(Ah + aoff, base + (size_t)ebase * 8);
      lds_cp16(Bh + boff, base + 4096 + (size_t)ebase * 8);
    }
  };

  STAGE(0, 0);
  __syncthreads();
  int cur = 0;
  for (int k0 = 0; k0 < K; k0 += 32) {
    if (k0 + 32 < K) STAGE(cur ^ 1, k0 + 32);
    const ushort* sAh = sm + cur * 8192;
    const ushort* sBh = sAh + 4096;
    s8v fa[4], fb[4];
#pragma unroll
    for (int u = 0; u < 4; ++u) {
      fa[u] = *(const s8v*)(sAh + (((wy * 64 + u * 16 + lrow) * 4 + slot) * 8));
      fb[u] = *(const s8v*)(sBh + (((wx * 64 + u * 16 + lrow) * 4 + slot) * 8));
    }
#pragma unroll
    for (int mt = 0; mt < 4; ++mt)
#pragma unroll
      for (int nt = 0; nt < 4; ++nt)
        acc[mt][nt] = __builtin_amdgcn_mfma_f32_16x16x32_bf16(fa[mt], fb[nt], acc[mt][nt], 0, 0, 0);
    __syncthreads();
    cur ^= 1;
  }
#pragma unroll
  for (int mt = 0; mt < 4; ++mt) {
#pragma unroll
    for (int i = 0; i < 4; ++i) {
      int r = m0 + wy * 64 + mt * 16 + lq * 4 + i;
      if (r < M) {
#pragma unroll
        for (int nt = 0; nt < 4; ++nt) {
          int c = n0 + wx * 64 + nt * 16 + lrow;
          float v = acc[mt][nt][i];
          if (bias) v += bias[c];
          C[(size_t)r * N + c] = v;
        }
      }
    }
  }
}

// ---------- adaptive-pool router v2: grid (200, 4) x 256 threads -> all CUs busy ----------
__global__ __launch_bounds__(256)
void pool_router2_kernel(const float* __restrict__ qkv, float* __restrict__ router) {
  int bm = blockIdx.x;                 // b*25 + m
  int b = bm / 25, m = bm % 25;
  int p = m / 5, q = m % 5;
  int sp = (p * 32) / 5, ep = ((p + 1) * 32 + 4) / 5;
  int sq = (q * 32) / 5, eq = ((q + 1) * 32 + 4) / 5;
  float inv = 1.0f / (float)((ep - sp) * (eq - sq));
  int c = blockIdx.y * 256 + threadIdx.x;
  float s0 = 0.f;
  for (int hh = sp; hh < ep; ++hh)
    for (int ww = sq; ww < eq; ++ww)
      s0 += qkv[(size_t)(b * NN + hh * 32 + ww) * 3072 + c];
  router[(size_t)bm * 1024 + c] = s0 * inv;
}

// ---------- fused router logits + coalesced rlogT/gateT + argmax assign ----------
__global__ __launch_bounds__(256)
void rg_fused_kernel(const float* __restrict__ qkv, const float* __restrict__ router,
                     float* __restrict__ rlog, float* __restrict__ rlogT,
                     float* __restrict__ gateT,
                     int* __restrict__ cnt, int* __restrict__ qlist) {
  __shared__ float sQ[64 * 68];        // pitch 68 -> b128 reads conflict-free
  __shared__ float sK[64 * 68];
  __shared__ float sR[25 * 64];
  __shared__ float sG[64 * 27];        // gate tile, odd-ish pitch
  int bh = blockIdx.x, s = blockIdx.y;
  int b = bh >> 4, h = bh & 15;
  int base = s * 64, seglen = min(64, NN - base);
  int t = threadIdx.x;
  for (int e = t; e < 400; e += 256) {           // r: 25 rows x 16 float4
    int m = e >> 4, c4 = e & 15;
    *(float4*)&sR[m * 64 + c4 * 4] =
        *(const float4*)(router + (size_t)(b * 25 + m) * 1024 + h * 64 + c4 * 4);
  }
  for (int e = t; e < seglen * 16; e += 256) {   // q,k tiles coalesced
    int row = e >> 4, c4 = e & 15;
    const float* src = qkv + (size_t)(b * NN + base + row) * 3072 + h * 64 + c4 * 4;
    *(float4*)&sQ[row * 68 + c4 * 4] = *(const float4*)(src);
    *(float4*)&sK[row * 68 + c4 * 4] = *(const float4*)(src + 1024);
  }
  __syncthreads();
  int nl = t & 63, w = t >> 6;
  float kl[7];                         // k-logits, statically indexed (rule #20)
#pragma unroll
  for (int j = 0; j < 7; ++j) kl[j] = 0.f;
  if (nl < seglen) {
    float4 rowreg[16];
#pragma unroll
    for (int c4 = 0; c4 < 16; ++c4) rowreg[c4] = *(const float4*)&sQ[nl * 68 + c4 * 4];
    for (int m = w; m < 25; m += 4) {
      const float* rp = &sR[m * 64];
      float a = 0.f;
#pragma unroll
      for (int c4 = 0; c4 < 16; ++c4) {
        float4 r4 = *(const float4*)(rp + c4 * 4);        // broadcast within wave
        a += rowreg[c4].x * r4.x + rowreg[c4].y * r4.y +
             rowreg[c4].z * r4.z + rowreg[c4].w * r4.w;
      }
      sG[nl * 27 + m] = a;
    }
#pragma unroll
    for (int c4 = 0; c4 < 16; ++c4) rowreg[c4] = *(const float4*)&sK[nl * 68 + c4 * 4];
#pragma unroll
    for (int j = 0; j < 7; ++j) {
      int m = w + 4 * j;
      if (m < 25) {
        const float* rp = &sR[m * 64];
        float a = 0.f;
#pragma unroll
        for (int c4 = 0; c4 < 16; ++c4) {
          float4 r4 = *(const float4*)(rp + c4 * 4);
          a += rowreg[c4].x * r4.x + rowreg[c4].y * r4.y +
               rowreg[c4].z * r4.z + rowreg[c4].w * r4.w;
        }
        rlog[(size_t)(bh * 25 + m) * NN + base + nl] = a;   // coalesced per m
        kl[j] = a;
      }
    }
  }
  __syncthreads();                     // A: all sQ reads complete -> safe to reuse
  float* sT = sQ;                      // [64][26] scratch for rlogT transpose
  if (nl < seglen) {
#pragma unroll
    for (int j = 0; j < 7; ++j) {
      int m = w + 4 * j;
      if (m < 25) sT[nl * 26 + m] = kl[j];
    }
  }
  __syncthreads();                     // B: sT complete (sG stable since before A)
  {
    // rlogT [seglen x 25] target region is exactly linear -> fully coalesced dwords
    float* dst = rlogT + (size_t)(bh * NN + base) * 25;
    for (int i = t; i < seglen * 25; i += 256) {
      int row = i / 25, m = i - row * 25;
      dst[i] = sT[row * 26 + m];
    }
  }
  {
    // gateT [seglen x GPITCH] contiguous dump from sG (padding lanes write 0, never read)
    float* dst = gateT + (size_t)(bh * NN + base) * GPITCH;
    for (int i = t; i < seglen * GPITCH; i += 256) {
      int row = i / GPITCH, m = i - row * GPITCH;
      dst[i] = (m < 25) ? sG[row * 27 + m] : 0.f;
    }
  }
  if (t < seglen) {
    const float* gp = &sG[t * 27];
    float best = -INFINITY; int bi = 0;
#pragma unroll
    for (int m = 0; m < 25; ++m) {
      float v = gp[m];
      if (v > best) { best = v; bi = m; }      // strict > : first-max, matches jnp.argmax
    }
    int pos = atomicAdd(&cnt[bh * 25 + bi], 1);
    qlist[(bh * 25 + bi) * NN + pos] = base + t;
  }
}

// ---------- top-25 of each rlog row + softmax row stats (one wave per row) ----------
__global__ void topk2_kernel(const float* __restrict__ rlog, int* __restrict__ topk,
                             float* __restrict__ rowMax, float* __restrict__ rowRcp) {
  int row = blockIdx.x;                // (b*16+h)*25+m
  int l = threadIdx.x;                 // 0..63
  const float* src = rlog + (size_t)row * NN;
  float vals[17];
#pragma unroll
  for (int i = 0; i < 17; ++i) {
    int n = l + i * 64;
    vals[i] = (n < NN) ? src[n] : -INFINITY;
  }
  {
    float mx = vals[0];
#pragma unroll
    for (int i = 1; i < 17; ++i) mx = fmaxf(mx, vals[i]);
#pragma unroll
    for (int off = 32; off; off >>= 1) mx = fmaxf(mx, __shfl_xor(mx, off));
    float mxs = mx * SCALE;
    float sum = 0.f;
#pragma unroll
    for (int i = 0; i < 17; ++i) sum += __expf(vals[i] * SCALE - mxs);  // exp(-inf)=0
#pragma unroll
    for (int off = 32; off; off >>= 1) sum += __shfl_xor(sum, off);
    if (l == 0) { rowMax[row] = mxs; rowRcp[row] = 1.0f / sum; }
  }
  int* out = topk + row * 25;
  for (int r = 0; r < 25; ++r) {
    float best = vals[0]; int bi = 0;
#pragma unroll
    for (int i = 1; i < 17; ++i)
      if (vals[i] > best) { best = vals[i]; bi = i; }
    int bn = l + bi * 64;
#pragma unroll
    for (int off = 32; off; off >>= 1) {
      float ov = __shfl_down(best, off);
      int on = __shfl_down(bn, off);
      if (ov > best || (ov == best && on < bn)) { best = ov; bn = on; }
    }
    bn = __shfl(bn, 0);
    if (l == 0) out[r] = bn;
    if ((bn & 63) == l) vals[bn >> 6] = -INFINITY;
  }
}

// ---------- agent value v7: V read ONCE; per-n contiguous rlogT weights; LDS wave-reduce ----------
__global__ __launch_bounds__(256)
void agent_value7_kernel(const float* __restrict__ qkv, const float* __restrict__ rlogT,
                         const float* __restrict__ rowMax, const float* __restrict__ rowRcp,
                         float* __restrict__ av) {
  __shared__ float red[4][25][64];     // 25.6 KB
  int bh = blockIdx.x, sl = blockIdx.y;
  int w = threadIdx.x >> 6, l = threadIdx.x & 63;
  int b = bh >> 4, h = bh & 15;
  int n0 = (sl * 4 + w) * 32;
  int n1 = (sl == 7 && w == 3) ? NN : n0 + 32;
  float mxs[25];
#pragma unroll
  for (int m = 0; m < 25; ++m) mxs[m] = rowMax[bh * 25 + m];
  const float* vb = qkv + (size_t)b * NN * 3072 + 2048 + h * 64 + l;
  const float* rT = rlogT + (size_t)bh * NN * 25;
  float acc[25];
#pragma unroll
  for (int m = 0; m < 25; ++m) acc[m] = 0.f;
  for (int n = n0; n < n1; ++n) {
    float v = vb[(size_t)n * 3072];              // coalesced 256B row, read once
    const float* r = rT + (size_t)n * 25;        // wave-uniform contiguous 25 floats
#pragma unroll
    for (int m = 0; m < 25; ++m)
      acc[m] += __expf(r[m] * SCALE - mxs[m]) * v;
  }
#pragma unroll
  for (int m = 0; m < 25; ++m) red[w][m][l] = acc[m];
  __syncthreads();
  for (int i = threadIdx.x; i < 1600; i += 256) {
    int m = i >> 6, ll = i & 63;
    float s = red[0][m][ll] + red[1][m][ll] + red[2][m][ll] + red[3][m][ll];
    atomicAdd(&av[((size_t)bh * 25 + m) * 64 + ll], s * rowRcp[bh * 25 + m]);
  }
}

// ---------- mixed attention v11: drop sA staging (AV is wave-uniform + L2-hot) ----------
// LDS 19.2KB -> 12.8KB: 8 -> 12 blocks/CU (+50% TLP for the scattered q4/serial chain).
__global__ __launch_bounds__(64)
void mixed_attn11_kernel(const float* __restrict__ qkv, const float* __restrict__ gateT,
                         const int* __restrict__ topk, const float* __restrict__ av,
                         const int* __restrict__ cnt, const int* __restrict__ qlist,
                         ushort* __restrict__ attn) {
  __shared__ float sK[25 * 64];
  __shared__ float sV[25 * 64];
  int e = blockIdx.x, bh = blockIdx.y;
  int c0 = blockIdx.z * 64;
  int ce = cnt[bh * 25 + e];
  if (c0 >= ce) return;
  int b = bh >> 4, h = bh & 15;
  int l = threadIdx.x;                 // 64 threads = 1 wave
  const int* tkp = topk + bh * 625 + e * 25;
  const float* qb = qkv + (size_t)b * NN * 3072 + h * 64;
  const int* ql = qlist + (bh * 25 + e) * NN;
  const float* avb = av + (size_t)bh * 25 * 64;

  // ---- early-issue per-lane loads: q row (scattered) + gate row; in flight during staging ----
  int qi = c0 + l;
  bool act = qi < ce;
  int n = ql[act ? qi : c0];
  const float* qr = qb + (size_t)n * 3072;
  float4 q4[16];
#pragma unroll
  for (int d4 = 0; d4 < 16; ++d4) q4[d4] = *(const float4*)(qr + d4 * 4);
  const float* gr = gateT + ((size_t)bh * NN + n) * GPITCH;
  float4 gv0 = *(const float4*)(gr);
  float4 gv1 = *(const float4*)(gr + 4);
  float4 gv2 = *(const float4*)(gr + 8);
  float4 gv3 = *(const float4*)(gr + 12);
  float4 gv4 = *(const float4*)(gr + 16);
  float4 gv5 = *(const float4*)(gr + 20);
  float g24 = gr[24];

  // ---- cooperative stage (coalesced): 25 selected K rows + V rows ----
  for (int i = l; i < 400; i += 64) {
    int row = i >> 4, c4 = (i & 15) * 4;
    const float* src = qb + (size_t)tkp[row] * 3072 + 1024 + c4;
    *(float4*)&sK[row * 64 + c4] = *(const float4*)(src);
    *(float4*)&sV[row * 64 + c4] = *(const float4*)(src + 1024);
  }
  __syncthreads();   // drains staging AND the early-issued q4/gate loads together

  // ---- pass 1: all 50 logits into registers ----
  float myW[50];
  myW[0] = gv0.x; myW[1] = gv0.y; myW[2] = gv0.z; myW[3] = gv0.w;
  myW[4] = gv1.x; myW[5] = gv1.y; myW[6] = gv1.z; myW[7] = gv1.w;
  myW[8] = gv2.x; myW[9] = gv2.y; myW[10] = gv2.z; myW[11] = gv2.w;
  myW[12] = gv3.x; myW[13] = gv3.y; myW[14] = gv3.z; myW[15] = gv3.w;
  myW[16] = gv4.x; myW[17] = gv4.y; myW[18] = gv4.z; myW[19] = gv4.w;
  myW[20] = gv5.x; myW[21] = gv5.y; myW[22] = gv5.z; myW[23] = gv5.w;
  myW[24] = g24;
#pragma unroll
  for (int m = 0; m < 25; ++m) myW[m] *= SCALE;
#pragma unroll
  for (int j = 0; j < 25; ++j) {
    const float4* kr = (const float4*)&sK[j * 64];
    float a = 0.f;
#pragma unroll
    for (int d4 = 0; d4 < 16; ++d4) {
      float4 k4 = kr[d4];
      a += q4[d4].x * k4.x + q4[d4].y * k4.y + q4[d4].z * k4.z + q4[d4].w * k4.w;
    }
    myW[25 + j] = a * SCALE;
  }
  // ---- softmax over 50 (unnormalized exps; normalize at store) ----
  float mx = myW[0];
#pragma unroll
  for (int i = 1; i < 50; ++i) mx = fmaxf(mx, myW[i]);
  float tot = 0.f;
#pragma unroll
  for (int i = 0; i < 50; ++i) { float w = __expf(myW[i] - mx); myW[i] = w; tot += w; }
  float rcp = 1.0f / tot;

  // ---- pass 2: output accumulate; AV via wave-uniform global reads (scalar path, L2-hot) ----
  float4 o[16];
#pragma unroll
  for (int d4 = 0; d4 < 16; ++d4) o[d4] = make_float4(0.f, 0.f, 0.f, 0.f);
#pragma unroll
  for (int m = 0; m < 25; ++m) {
    const float4* src = (const float4*)(avb + m * 64);     // wave-uniform
    float wv = myW[m];
#pragma unroll
    for (int d4 = 0; d4 < 16; ++d4) {
      float4 a4 = src[d4];
      o[d4].x += wv * a4.x; o[d4].y += wv * a4.y;
      o[d4].z += wv * a4.z; o[d4].w += wv * a4.w;
    }
  }
#pragma unroll
  for (int j = 0; j < 25; ++j) {
    const float4* src = (const float4*)&sV[j * 64];
    float wv = myW[25 + j];
#pragma unroll
    for (int d4 = 0; d4 < 16; ++d4) {
      float4 a4 = src[d4];
      o[d4].x += wv * a4.x; o[d4].y += wv * a4.y;
      o[d4].z += wv * a4.z; o[d4].w += wv * a4.w;
    }
  }
  if (act) {
    ushort* orow = attn + (size_t)(b * NN + n) * 1024 + h * 64;
#pragma unroll
    for (int d4 = 0; d4 < 16; ++d4) {
      ushort4 u;
      u.x = f2bf(o[d4].x * rcp); u.y = f2bf(o[d4].y * rcp);
      u.z = f2bf(o[d4].z * rcp); u.w = f2bf(o[d4].w * rcp);
      *(ushort4*)(orow + d4 * 4) = u;
    }
  }
}

// ---------- launch ----------
extern "C" void kernel_launch(void* const* d_in, const int* in_sizes, int n_in,
                              void* d_out, int out_size, void* d_ws, size_t ws_size,
                              hipStream_t stream) {
  const float* x = (const float*)d_in[0];
  const float* Wqkv = (const float*)d_in[1];
  const float* Wproj = (const float*)d_in[2];
  const float* bproj = (const float*)d_in[3];

  char* ws = (char*)d_ws;
  size_t off = 0;
  float* qkv = (float*)(ws + off);      off += (size_t)MROWS * 3072 * 4;    // 100,761,600
  ushort* xh = (ushort*)(ws + off);     off += (size_t)MROWS * 1024 * 2;    // 16,793,600
  ushort* xl = (ushort*)(ws + off);     off += (size_t)MROWS * 1024 * 2;
  ushort* Wth = (ushort*)(ws + off);    off += (size_t)3072 * 1024 * 2;     // 6,291,456
  ushort* Wtl = (ushort*)(ws + off);    off += (size_t)3072 * 1024 * 2;
  ushort* WpT = (ushort*)(ws + off);    off += (size_t)1024 * 1024 * 2;     // 2,097,152
  float* router = (float*)(ws + off);   off += (size_t)BB * 25 * 1024 * 4;  // 819,200
  float* rlog = (float*)(ws + off);     off += (size_t)BB * HH * 25 * NN * 4; // 13,120,000
  float* rlogT = (float*)(ws + off);    off += (size_t)BB * HH * NN * 25 * 4; // 13,120,000
  int* topk = (int*)(ws + off);         off += (size_t)BB * HH * 25 * 25 * 4; // 320,000
  float* av = (float*)(ws + off);       off += (size_t)BB * HH * 25 * 64 * 4; // 819,200
  ushort* attn = (ushort*)(ws + off);   off += (size_t)MROWS * 1024 * 2;
  float* rowMax = (float*)(ws + off);   off += (size_t)BB * HH * 25 * 4;    // 12,800
  float* rowRcp = (float*)(ws + off);   off += (size_t)BB * HH * 25 * 4;

  // xh/xl are dead after the qkv GEMM -> reuse for routing metadata
  float* gateT = (float*)xh;                               // 128*1025*28*4 = 14,694,400 B
  int* cnt = (int*)((char*)xh + 14694400);                 // 12,800 B (total <= 16,793,600)
  int* qlist = (int*)xl;                                   // 13,120,000 B

  split_x_kernel<<<8200, 256, 0, stream>>>(x, xh, xl, 2099200);
  transpose_split_kernel<<<dim3(96, 32), dim3(32, 8), 0, stream>>>(Wqkv, Wth, Wtl, 1024, 3072);
  transpose_split_kernel<<<dim3(32, 32), dim3(32, 8), 0, stream>>>(Wproj, WpT, nullptr, 1024, 1024);
  // qkv = x @ Wqkv : bf16x3 for q,k columns (<2048), plain bf16 for v columns
  gemm_dbuf_kernel<<<dim3(24, 65), 256, 0, stream>>>(xh, xl, Wth, Wtl, qkv, nullptr,
                                                     MROWS, 3072, 1024, 2048);
  pool_router2_kernel<<<dim3(BB * 25, 4), 256, 0, stream>>>(qkv, router);
  hipMemsetAsync(cnt, 0, 3200 * 4, stream);
  hipMemsetAsync(av, 0, (size_t)BB * HH * 25 * 64 * 4, stream);
  rg_fused_kernel<<<dim3(128, 17), 256, 0, stream>>>(qkv, router, rlog, rlogT, gateT, cnt, qlist);
  topk2_kernel<<<BB * HH * 25, 64, 0, stream>>>(rlog, topk, rowMax, rowRcp);
  agent_value7_kernel<<<dim3(128, 8), 256, 0, stream>>>(qkv, rlogT, rowMax, rowRcp, av);
  mixed_attn11_kernel<<<dim3(25, 128, 17), 64, 0, stream>>>(qkv, gateT, topk, av, cnt, qlist, attn);
  // out = attn @ Wproj + bproj : plain bf16 (32KB-LDS kernel -> 5 blocks/CU, no tail round)
  gemm_dbuf_plain_kernel<<<dim3(8, 65), 256, 0, stream>>>(attn, WpT, (float*)d_out, bproj,
                                                          MROWS, 1024, 1024);
}

// Round 16
// 540.516 us; speedup vs baseline: 1.1003x; 1.0744x over previous
//
#include <hip/hip_runtime.h>
#include <cstdint>

#define DEV static __device__ __forceinline__

typedef float f4v __attribute__((ext_vector_type(4)));
typedef short s8v __attribute__((ext_vector_type(8)));

// ---------- helpers ----------
DEV ushort f2bf(float f) {
  uint32_t u = __float_as_uint(f);
  uint32_t r = (u + 0x7FFFu + ((u >> 16) & 1u)) >> 16;   // RTNE
  return (ushort)r;
}
DEV float bf2f(ushort h) { return __uint_as_float(((uint32_t)h) << 16); }

DEV void lds_cp16(const void* g, void* l) {
  __builtin_amdgcn_global_load_lds((const __attribute__((address_space(1))) void*)g,
                                   (__attribute__((address_space(3))) void*)l, 16, 0, 0);
}

// ---------- constants ----------
#define BB 8
#define NN 1025
#define CC 1024
#define HH 16
#define DD 64
#define MM 25
#define KK 25
#define MROWS 8200          // B*N
#define SCALE 0.125f
#define GPITCH 28           // gateT row pitch (floats) -> 112B, 16B-aligned

// ---------- split x into bf16 hi/lo ----------
__global__ void split_x_kernel(const float* __restrict__ x, ushort* __restrict__ hi,
                               ushort* __restrict__ lo, int n4) {
  int i = blockIdx.x * 256 + threadIdx.x;
  if (i >= n4) return;
  float4 f = ((const float4*)x)[i];
  ushort4 h, l;
  h.x = f2bf(f.x); l.x = f2bf(f.x - bf2f(h.x));
  h.y = f2bf(f.y); l.y = f2bf(f.y - bf2f(h.y));
  h.z = f2bf(f.z); l.z = f2bf(f.z - bf2f(h.z));
  h.w = f2bf(f.w); l.w = f2bf(f.w - bf2f(h.w));
  ((ushort4*)hi)[i] = h;
  ((ushort4*)lo)[i] = l;
}

// ---------- transpose W[K][N] -> Wt[N][K] bf16 hi (+optional lo) ----------
__global__ void transpose_split_kernel(const float* __restrict__ W, ushort* __restrict__ hi,
                                       ushort* __restrict__ lo, int K, int N) {
  __shared__ float tile[32][33];
  int nb = blockIdx.x * 32, kb = blockIdx.y * 32;
  int tx = threadIdx.x, ty = threadIdx.y;      // 32x8
  for (int r = ty; r < 32; r += 8) tile[r][tx] = W[(size_t)(kb + r) * N + nb + tx];
  __syncthreads();
  for (int r = ty; r < 32; r += 8) {
    float f = tile[tx][r];                     // W[kb+tx][nb+r] -> Wt[nb+r][kb+tx]
    ushort h = f2bf(f);
    hi[(size_t)(nb + r) * K + kb + tx] = h;
    if (lo) lo[(size_t)(nb + r) * K + kb + tx] = f2bf(f - bf2f(h));
  }
}

// ---------- MFMA GEMM v3: 128x128 tile, double-buffered LDS, 2-phase pipeline (bf16x3) ----------
__global__ __launch_bounds__(256)
void gemm_dbuf_kernel(const ushort* __restrict__ Ah, const ushort* __restrict__ Al,
                      const ushort* __restrict__ Bh, const ushort* __restrict__ Bl,
                      float* __restrict__ C, const float* __restrict__ bias,
                      int M, int N, int K, int loN) {
  __shared__ ushort sm[32768];                 // 65536 B
  const int t = threadIdx.x;
  const int m0 = blockIdx.y * 128, n0 = blockIdx.x * 128;
  const bool three = (n0 < loN);
  const int lane = t & 63, wid = t >> 6;
  const int wy = wid >> 1, wx = wid & 1;       // 2x2 waves of 64x64
  const int lrow = lane & 15, lq = lane >> 4;
  const int slot = lq ^ ((lrow >> 1) & 3);     // fragment read swizzle

  f4v acc[4][4];
#pragma unroll
  for (int a = 0; a < 4; ++a)
#pragma unroll
    for (int b = 0; b < 4; ++b) acc[a][b] = (f4v)0.f;

  auto STAGE = [&](int p, int k0) {
    ushort* base = sm + p * 16384;
#pragma unroll
    for (int i = 0; i < 2; ++i) {
      int e = i * 256 + t;
      int row = e >> 2;
      int cgs = (e & 3) ^ ((e >> 3) & 3);      // staged k-group (XOR swizzle)
      int ebase = i * 256 + (t & 192);         // wave-uniform base
      size_t aoff = (size_t)min(m0 + row, M - 1) * K + k0 + cgs * 8;
      size_t boff = (size_t)(n0 + row) * K + k0 + cgs * 8;
      lds_cp16(Ah + aoff, base + (size_t)ebase * 8);
      lds_cp16(Bh + boff, base + 8192 + (size_t)ebase * 8);
      if (three) {
        lds_cp16(Al + aoff, base + 4096 + (size_t)ebase * 8);
        lds_cp16(Bl + boff, base + 12288 + (size_t)ebase * 8);
      }
    }
  };

  STAGE(0, 0);
  __syncthreads();
  int cur = 0;
  for (int k0 = 0; k0 < K; k0 += 32) {
    if (k0 + 32 < K) STAGE(cur ^ 1, k0 + 32);  // issue next tile (overlaps compute below)
    const ushort* sAh = sm + cur * 16384;
    const ushort* sAl = sAh + 4096;
    const ushort* sBh = sAh + 8192;
    const ushort* sBl = sAh + 12288;
    s8v fa[4], fb[4];
#pragma unroll
    for (int u = 0; u < 4; ++u) {
      fa[u] = *(const s8v*)(sAh + (((wy * 64 + u * 16 + lrow) * 4 + slot) * 8));
      fb[u] = *(const s8v*)(sBh + (((wx * 64 + u * 16 + lrow) * 4 + slot) * 8));
    }
#pragma unroll
    for (int mt = 0; mt < 4; ++mt)
#pragma unroll
      for (int nt = 0; nt < 4; ++nt)
        acc[mt][nt] = __builtin_amdgcn_mfma_f32_16x16x32_bf16(fa[mt], fb[nt], acc[mt][nt], 0, 0, 0);
    if (three) {
      s8v la[4], lb[4];
#pragma unroll
      for (int u = 0; u < 4; ++u) {
        la[u] = *(const s8v*)(sAl + (((wy * 64 + u * 16 + lrow) * 4 + slot) * 8));
        lb[u] = *(const s8v*)(sBl + (((wx * 64 + u * 16 + lrow) * 4 + slot) * 8));
      }
#pragma unroll
      for (int mt = 0; mt < 4; ++mt)
#pragma unroll
        for (int nt = 0; nt < 4; ++nt) {
          acc[mt][nt] = __builtin_amdgcn_mfma_f32_16x16x32_bf16(fa[mt], lb[nt], acc[mt][nt], 0, 0, 0);
          acc[mt][nt] = __builtin_amdgcn_mfma_f32_16x16x32_bf16(la[mt], fb[nt], acc[mt][nt], 0, 0, 0);
        }
    }
    __syncthreads();   // drains next-tile loads + fences read-before-overwrite
    cur ^= 1;
  }
  // epilogue: C/D layout col=lane&15, row=(lane>>4)*4+i  [m89/m91-verified]
#pragma unroll
  for (int mt = 0; mt < 4; ++mt) {
#pragma unroll
    for (int i = 0; i < 4; ++i) {
      int r = m0 + wy * 64 + mt * 16 + lq * 4 + i;
      if (r < M) {
#pragma unroll
        for (int nt = 0; nt < 4; ++nt) {
          int c = n0 + wx * 64 + nt * 16 + lrow;
          float v = acc[mt][nt][i];
          if (bias) v += bias[c];
          C[(size_t)r * N + c] = v;
        }
      }
    }
  }
}

// ---------- MFMA GEMM plain: 128x128 dbuf, NO hi/lo split -> 32KB LDS, 5 blocks/CU ----------
__global__ __launch_bounds__(256)
void gemm_dbuf_plain_kernel(const ushort* __restrict__ Ah, const ushort* __restrict__ Bh,
                            float* __restrict__ C, const float* __restrict__ bias,
                            int M, int N, int K) {
  __shared__ ushort sm[16384];                 // 32768 B: 2 bufs x (A 8KB | B 8KB)
  const int t = threadIdx.x;
  const int m0 = blockIdx.y * 128, n0 = blockIdx.x * 128;
  const int lane = t & 63, wid = t >> 6;
  const int wy = wid >> 1, wx = wid & 1;
  const int lrow = lane & 15, lq = lane >> 4;
  const int slot = lq ^ ((lrow >> 1) & 3);

  f4v acc[4][4];
#pragma unroll
  for (int a = 0; a < 4; ++a)
#pragma unroll
    for (int b = 0; b < 4; ++b) acc[a][b] = (f4v)0.f;

  auto STAGE = [&](int p, int k0) {
    ushort* base = sm + p * 8192;
#pragma unroll
    for (int i = 0; i < 2; ++i) {
      int e = i * 256 + t;
      int row = e >> 2;
      int cgs = (e & 3) ^ ((e >> 3) & 3);
      int ebase = i * 256 + (t & 192);
      size_t aoff = (size_t)min(m0 + row, M - 1) * K + k0 + cgs * 8;
      size_t boff = (size_t)(n0 + row) * K + k0 + cgs * 8;
      lds_cp16(Ah + aoff, base + (size_t)ebase * 8);
      lds_cp16(Bh + boff, base + 4096 + (size_t)ebase * 8);
    }
  };

  STAGE(0, 0);
  __syncthreads();
  int cur = 0;
  for (int k0 = 0; k0 < K; k0 += 32) {
    if (k0 + 32 < K) STAGE(cur ^ 1, k0 + 32);
    const ushort* sAh = sm + cur * 8192;
    const ushort* sBh = sAh + 4096;
    s8v fa[4], fb[4];
#pragma unroll
    for (int u = 0; u < 4; ++u) {
      fa[u] = *(const s8v*)(sAh + (((wy * 64 + u * 16 + lrow) * 4 + slot) * 8));
      fb[u] = *(const s8v*)(sBh + (((wx * 64 + u * 16 + lrow) * 4 + slot) * 8));
    }
#pragma unroll
    for (int mt = 0; mt < 4; ++mt)
#pragma unroll
      for (int nt = 0; nt < 4; ++nt)
        acc[mt][nt] = __builtin_amdgcn_mfma_f32_16x16x32_bf16(fa[mt], fb[nt], acc[mt][nt], 0, 0, 0);
    __syncthreads();
    cur ^= 1;
  }
#pragma unroll
  for (int mt = 0; mt < 4; ++mt) {
#pragma unroll
    for (int i = 0; i < 4; ++i) {
      int r = m0 + wy * 64 + mt * 16 + lq * 4 + i;
      if (r < M) {
#pragma unroll
        for (int nt = 0; nt < 4; ++nt) {
          int c = n0 + wx * 64 + nt * 16 + lrow;
          float v = acc[mt][nt][i];
          if (bias) v += bias[c];
          C[(size_t)r * N + c] = v;
        }
      }
    }
  }
}

// ---------- adaptive-pool router v2: grid (200, 4) x 256 threads -> all CUs busy ----------
__global__ __launch_bounds__(256)
void pool_router2_kernel(const float* __restrict__ qkv, float* __restrict__ router) {
  int bm = blockIdx.x;                 // b*25 + m
  int b = bm / 25, m = bm % 25;
  int p = m / 5, q = m % 5;
  int sp = (p * 32) / 5, ep = ((p + 1) * 32 + 4) / 5;
  int sq = (q * 32) / 5, eq = ((q + 1) * 32 + 4) / 5;
  float inv = 1.0f / (float)((ep - sp) * (eq - sq));
  int c = blockIdx.y * 256 + threadIdx.x;
  float s0 = 0.f;
  for (int hh = sp; hh < ep; ++hh)
    for (int ww = sq; ww < eq; ++ww)
      s0 += qkv[(size_t)(b * NN + hh * 32 + ww) * 3072 + c];
  router[(size_t)bm * 1024 + c] = s0 * inv;
}

// ---------- fused router logits + coalesced rlogT/gateT + argmax assign ----------
__global__ __launch_bounds__(256)
void rg_fused_kernel(const float* __restrict__ qkv, const float* __restrict__ router,
                     float* __restrict__ rlog, float* __restrict__ rlogT,
                     float* __restrict__ gateT,
                     int* __restrict__ cnt, int* __restrict__ qlist) {
  __shared__ float sQ[64 * 68];        // pitch 68 -> b128 reads conflict-free
  __shared__ float sK[64 * 68];
  __shared__ float sR[25 * 64];
  __shared__ float sG[64 * 27];        // gate tile, odd-ish pitch
  int bh = blockIdx.x, s = blockIdx.y;
  int b = bh >> 4, h = bh & 15;
  int base = s * 64, seglen = min(64, NN - base);
  int t = threadIdx.x;
  for (int e = t; e < 400; e += 256) {           // r: 25 rows x 16 float4
    int m = e >> 4, c4 = e & 15;
    *(float4*)&sR[m * 64 + c4 * 4] =
        *(const float4*)(router + (size_t)(b * 25 + m) * 1024 + h * 64 + c4 * 4);
  }
  for (int e = t; e < seglen * 16; e += 256) {   // q,k tiles coalesced
    int row = e >> 4, c4 = e & 15;
    const float* src = qkv + (size_t)(b * NN + base + row) * 3072 + h * 64 + c4 * 4;
    *(float4*)&sQ[row * 68 + c4 * 4] = *(const float4*)(src);
    *(float4*)&sK[row * 68 + c4 * 4] = *(const float4*)(src + 1024);
  }
  __syncthreads();
  int nl = t & 63, w = t >> 6;
  float kl[7];                         // k-logits, statically indexed (rule #20)
#pragma unroll
  for (int j = 0; j < 7; ++j) kl[j] = 0.f;
  if (nl < seglen) {
    float4 rowreg[16];
#pragma unroll
    for (int c4 = 0; c4 < 16; ++c4) rowreg[c4] = *(const float4*)&sQ[nl * 68 + c4 * 4];
    for (int m = w; m < 25; m += 4) {
      const float* rp = &sR[m * 64];
      float a = 0.f;
#pragma unroll
      for (int c4 = 0; c4 < 16; ++c4) {
        float4 r4 = *(const float4*)(rp + c4 * 4);        // broadcast within wave
        a += rowreg[c4].x * r4.x + rowreg[c4].y * r4.y +
             rowreg[c4].z * r4.z + rowreg[c4].w * r4.w;
      }
      sG[nl * 27 + m] = a;
    }
#pragma unroll
    for (int c4 = 0; c4 < 16; ++c4) rowreg[c4] = *(const float4*)&sK[nl * 68 + c4 * 4];
#pragma unroll
    for (int j = 0; j < 7; ++j) {
      int m = w + 4 * j;
      if (m < 25) {
        const float* rp = &sR[m * 64];
        float a = 0.f;
#pragma unroll
        for (int c4 = 0; c4 < 16; ++c4) {
          float4 r4 = *(const float4*)(rp + c4 * 4);
          a += rowreg[c4].x * r4.x + rowreg[c4].y * r4.y +
               rowreg[c4].z * r4.z + rowreg[c4].w * r4.w;
        }
        rlog[(size_t)(bh * 25 + m) * NN + base + nl] = a;   // coalesced per m
        kl[j] = a;
      }
    }
  }
  __syncthreads();                     // A: all sQ reads complete -> safe to reuse
  float* sT = sQ;                      // [64][26] scratch for rlogT transpose
  if (nl < seglen) {
#pragma unroll
    for (int j = 0; j < 7; ++j) {
      int m = w + 4 * j;
      if (m < 25) sT[nl * 26 + m] = kl[j];
    }
  }
  __syncthreads();                     // B: sT complete (sG stable since before A)
  {
    // rlogT [seglen x 25] target region is exactly linear -> fully coalesced dwords
    float* dst = rlogT + (size_t)(bh * NN + base) * 25;
    for (int i = t; i < seglen * 25; i += 256) {
      int row = i / 25, m = i - row * 25;
      dst[i] = sT[row * 26 + m];
    }
  }
  {
    // gateT [seglen x GPITCH] contiguous dump from sG (padding lanes write 0, never read)
    float* dst = gateT + (size_t)(bh * NN + base) * GPITCH;
    for (int i = t; i < seglen * GPITCH; i += 256) {
      int row = i / GPITCH, m = i - row * GPITCH;
      dst[i] = (m < 25) ? sG[row * 27 + m] : 0.f;
    }
  }
  if (t < seglen) {
    const float* gp = &sG[t * 27];
    float best = -INFINITY; int bi = 0;
#pragma unroll
    for (int m = 0; m < 25; ++m) {
      float v = gp[m];
      if (v > best) { best = v; bi = m; }      // strict > : first-max, matches jnp.argmax
    }
    int pos = atomicAdd(&cnt[bh * 25 + bi], 1);
    qlist[(bh * 25 + bi) * NN + pos] = base + t;
  }
}

// ---------- top-25 of each rlog row + softmax row stats (one wave per row) ----------
__global__ void topk2_kernel(const float* __restrict__ rlog, int* __restrict__ topk,
                             float* __restrict__ rowMax, float* __restrict__ rowRcp) {
  int row = blockIdx.x;                // (b*16+h)*25+m
  int l = threadIdx.x;                 // 0..63
  const float* src = rlog + (size_t)row * NN;
  float vals[17];
#pragma unroll
  for (int i = 0; i < 17; ++i) {
    int n = l + i * 64;
    vals[i] = (n < NN) ? src[n] : -INFINITY;
  }
  {
    float mx = vals[0];
#pragma unroll
    for (int i = 1; i < 17; ++i) mx = fmaxf(mx, vals[i]);
#pragma unroll
    for (int off = 32; off; off >>= 1) mx = fmaxf(mx, __shfl_xor(mx, off));
    float mxs = mx * SCALE;
    float sum = 0.f;
#pragma unroll
    for (int i = 0; i < 17; ++i) sum += __expf(vals[i] * SCALE - mxs);  // exp(-inf)=0
#pragma unroll
    for (int off = 32; off; off >>= 1) sum += __shfl_xor(sum, off);
    if (l == 0) { rowMax[row] = mxs; rowRcp[row] = 1.0f / sum; }
  }
  int* out = topk + row * 25;
  for (int r = 0; r < 25; ++r) {
    float best = vals[0]; int bi = 0;
#pragma unroll
    for (int i = 1; i < 17; ++i)
      if (vals[i] > best) { best = vals[i]; bi = i; }
    int bn = l + bi * 64;
#pragma unroll
    for (int off = 32; off; off >>= 1) {
      float ov = __shfl_down(best, off);
      int on = __shfl_down(bn, off);
      if (ov > best || (ov == best && on < bn)) { best = ov; bn = on; }
    }
    bn = __shfl(bn, 0);
    if (l == 0) out[r] = bn;
    if ((bn & 63) == l) vals[bn >> 6] = -INFINITY;
  }
}

// ---------- agent value v7: V read ONCE; per-n contiguous rlogT weights; LDS wave-reduce ----------
__global__ __launch_bounds__(256)
void agent_value7_kernel(const float* __restrict__ qkv, const float* __restrict__ rlogT,
                         const float* __restrict__ rowMax, const float* __restrict__ rowRcp,
                         float* __restrict__ av) {
  __shared__ float red[4][25][64];     // 25.6 KB
  int bh = blockIdx.x, sl = blockIdx.y;
  int w = threadIdx.x >> 6, l = threadIdx.x & 63;
  int b = bh >> 4, h = bh & 15;
  int n0 = (sl * 4 + w) * 32;
  int n1 = (sl == 7 && w == 3) ? NN : n0 + 32;
  float mxs[25];
#pragma unroll
  for (int m = 0; m < 25; ++m) mxs[m] = rowMax[bh * 25 + m];
  const float* vb = qkv + (size_t)b * NN * 3072 + 2048 + h * 64 + l;
  const float* rT = rlogT + (size_t)bh * NN * 25;
  float acc[25];
#pragma unroll
  for (int m = 0; m < 25; ++m) acc[m] = 0.f;
  for (int n = n0; n < n1; ++n) {
    float v = vb[(size_t)n * 3072];              // coalesced 256B row, read once
    const float* r = rT + (size_t)n * 25;        // wave-uniform contiguous 25 floats
#pragma unroll
    for (int m = 0; m < 25; ++m)
      acc[m] += __expf(r[m] * SCALE - mxs[m]) * v;
  }
#pragma unroll
  for (int m = 0; m < 25; ++m) red[w][m][l] = acc[m];
  __syncthreads();
  for (int i = threadIdx.x; i < 1600; i += 256) {
    int m = i >> 6, ll = i & 63;
    float s = red[0][m][ll] + red[1][m][ll] + red[2][m][ll] + red[3][m][ll];
    atomicAdd(&av[((size_t)bh * 25 + m) * 64 + ll], s * rowRcp[bh * 25 + m]);
  }
}

// ---------- mixed attention v10 (restored): LDS-staged Ksel/Vsel/AV + early-issue q/gate ----------
__global__ __launch_bounds__(64)
void mixed_attn10_kernel(const float* __restrict__ qkv, const float* __restrict__ gateT,
                         const int* __restrict__ topk, const float* __restrict__ av,
                         const int* __restrict__ cnt, const int* __restrict__ qlist,
                         ushort* __restrict__ attn) {
  __shared__ float sK[25 * 64];
  __shared__ float sV[25 * 64];
  __shared__ float sA[25 * 64];
  int e = blockIdx.x, bh = blockIdx.y;
  int c0 = blockIdx.z * 64;
  int ce = cnt[bh * 25 + e];
  if (c0 >= ce) return;
  int b = bh >> 4, h = bh & 15;
  int l = threadIdx.x;                 // 64 threads = 1 wave
  const int* tkp = topk + bh * 625 + e * 25;
  const float* qb = qkv + (size_t)b * NN * 3072 + h * 64;
  const int* ql = qlist + (bh * 25 + e) * NN;

  // ---- early-issue per-lane loads: q row (scattered) + gate row; in flight during staging ----
  int qi = c0 + l;
  bool act = qi < ce;
  int n = ql[act ? qi : c0];
  const float* qr = qb + (size_t)n * 3072;
  float4 q4[16];
#pragma unroll
  for (int d4 = 0; d4 < 16; ++d4) q4[d4] = *(const float4*)(qr + d4 * 4);
  const float* gr = gateT + ((size_t)bh * NN + n) * GPITCH;
  float4 gv0 = *(const float4*)(gr);
  float4 gv1 = *(const float4*)(gr + 4);
  float4 gv2 = *(const float4*)(gr + 8);
  float4 gv3 = *(const float4*)(gr + 12);
  float4 gv4 = *(const float4*)(gr + 16);
  float4 gv5 = *(const float4*)(gr + 20);
  float g24 = gr[24];

  // ---- cooperative stage (coalesced): 25 K rows, 25 V rows, 25 AV rows ----
  for (int i = l; i < 400; i += 64) {
    int row = i >> 4, c4 = (i & 15) * 4;
    const float* src = qb + (size_t)tkp[row] * 3072 + 1024 + c4;
    *(float4*)&sK[row * 64 + c4] = *(const float4*)(src);
    *(float4*)&sV[row * 64 + c4] = *(const float4*)(src + 1024);
  }
  {
    const float* avb = av + (size_t)bh * 25 * 64;
    for (int i = l; i < 400; i += 64)
      *(float4*)&sA[i * 4] = *(const float4*)(avb + i * 4);
  }
  __syncthreads();   // drains staging AND the early-issued q4/gate loads together

  // ---- pass 1: all 50 logits into registers ----
  float myW[50];
  myW[0] = gv0.x; myW[1] = gv0.y; myW[2] = gv0.z; myW[3] = gv0.w;
  myW[4] = gv1.x; myW[5] = gv1.y; myW[6] = gv1.z; myW[7] = gv1.w;
  myW[8] = gv2.x; myW[9] = gv2.y; myW[10] = gv2.z; myW[11] = gv2.w;
  myW[12] = gv3.x; myW[13] = gv3.y; myW[14] = gv3.z; myW[15] = gv3.w;
  myW[16] = gv4.x; myW[17] = gv4.y; myW[18] = gv4.z; myW[19] = gv4.w;
  myW[20] = gv5.x; myW[21] = gv5.y; myW[22] = gv5.z; myW[23] = gv5.w;
  myW[24] = g24;
#pragma unroll
  for (int m = 0; m < 25; ++m) myW[m] *= SCALE;
#pragma unroll
  for (int j = 0; j < 25; ++j) {
    const float4* kr = (const float4*)&sK[j * 64];
    float a = 0.f;
#pragma unroll
    for (int d4 = 0; d4 < 16; ++d4) {
      float4 k4 = kr[d4];
      a += q4[d4].x * k4.x + q4[d4].y * k4.y + q4[d4].z * k4.z + q4[d4].w * k4.w;
    }
    myW[25 + j] = a * SCALE;
  }
  // ---- softmax over 50 (unnormalized exps; normalize at store) ----
  float mx = myW[0];
#pragma unroll
  for (int i = 1; i < 50; ++i) mx = fmaxf(mx, myW[i]);
  float tot = 0.f;
#pragma unroll
  for (int i = 0; i < 50; ++i) { float w = __expf(myW[i] - mx); myW[i] = w; tot += w; }
  float rcp = 1.0f / tot;

  // ---- pass 2: output accumulate from LDS ----
  float4 o[16];
#pragma unroll
  for (int d4 = 0; d4 < 16; ++d4) o[d4] = make_float4(0.f, 0.f, 0.f, 0.f);
#pragma unroll
  for (int m = 0; m < 25; ++m) {
    const float4* src = (const float4*)&sA[m * 64];
    float wv = myW[m];
#pragma unroll
    for (int d4 = 0; d4 < 16; ++d4) {
      float4 a4 = src[d4];
      o[d4].x += wv * a4.x; o[d4].y += wv * a4.y;
      o[d4].z += wv * a4.z; o[d4].w += wv * a4.w;
    }
  }
#pragma unroll
  for (int j = 0; j < 25; ++j) {
    const float4* src = (const float4*)&sV[j * 64];
    float wv = myW[25 + j];
#pragma unroll
    for (int d4 = 0; d4 < 16; ++d4) {
      float4 a4 = src[d4];
      o[d4].x += wv * a4.x; o[d4].y += wv * a4.y;
      o[d4].z += wv * a4.z; o[d4].w += wv * a4.w;
    }
  }
  if (act) {
    ushort* orow = attn + (size_t)(b * NN + n) * 1024 + h * 64;
#pragma unroll
    for (int d4 = 0; d4 < 16; ++d4) {
      ushort4 u;
      u.x = f2bf(o[d4].x * rcp); u.y = f2bf(o[d4].y * rcp);
      u.z = f2bf(o[d4].z * rcp); u.w = f2bf(o[d4].w * rcp);
      *(ushort4*)(orow + d4 * 4) = u;
    }
  }
}

// ---------- launch ----------
extern "C" void kernel_launch(void* const* d_in, const int* in_sizes, int n_in,
                              void* d_out, int out_size, void* d_ws, size_t ws_size,
                              hipStream_t stream) {
  const float* x = (const float*)d_in[0];
  const float* Wqkv = (const float*)d_in[1];
  const float* Wproj = (const float*)d_in[2];
  const float* bproj = (const float*)d_in[3];

  char* ws = (char*)d_ws;
  size_t off = 0;
  float* qkv = (float*)(ws + off);      off += (size_t)MROWS * 3072 * 4;    // 100,761,600
  ushort* xh = (ushort*)(ws + off);     off += (size_t)MROWS * 1024 * 2;    // 16,793,600
  ushort* xl = (ushort*)(ws + off);     off += (size_t)MROWS * 1024 * 2;
  ushort* Wth = (ushort*)(ws + off);    off += (size_t)3072 * 1024 * 2;     // 6,291,456
  ushort* Wtl = (ushort*)(ws + off);    off += (size_t)3072 * 1024 * 2;
  ushort* WpT = (ushort*)(ws + off);    off += (size_t)1024 * 1024 * 2;     // 2,097,152
  float* router = (float*)(ws + off);   off += (size_t)BB * 25 * 1024 * 4;  // 819,200
  float* rlog = (float*)(ws + off);     off += (size_t)BB * HH * 25 * NN * 4; // 13,120,000
  float* rlogT = (float*)(ws + off);    off += (size_t)BB * HH * NN * 25 * 4; // 13,120,000
  int* topk = (int*)(ws + off);         off += (size_t)BB * HH * 25 * 25 * 4; // 320,000
  float* av = (float*)(ws + off);       off += (size_t)BB * HH * 25 * 64 * 4; // 819,200
  ushort* attn = (ushort*)(ws + off);   off += (size_t)MROWS * 1024 * 2;
  float* rowMax = (float*)(ws + off);   off += (size_t)BB * HH * 25 * 4;    // 12,800
  float* rowRcp = (float*)(ws + off);   off += (size_t)BB * HH * 25 * 4;

  // xh/xl are dead after the qkv GEMM -> reuse for routing metadata
  float* gateT = (float*)xh;                               // 128*1025*28*4 = 14,694,400 B
  int* cnt = (int*)((char*)xh + 14694400);                 // 12,800 B (total <= 16,793,600)
  int* qlist = (int*)xl;                                   // 13,120,000 B

  split_x_kernel<<<8200, 256, 0, stream>>>(x, xh, xl, 2099200);
  transpose_split_kernel<<<dim3(96, 32), dim3(32, 8), 0, stream>>>(Wqkv, Wth, Wtl, 1024, 3072);
  transpose_split_kernel<<<dim3(32, 32), dim3(32, 8), 0, stream>>>(Wproj, WpT, nullptr, 1024, 1024);
  // qkv = x @ Wqkv : bf16x3 for q,k columns (<2048), plain bf16 for v columns
  gemm_dbuf_kernel<<<dim3(24, 65), 256, 0, stream>>>(xh, xl, Wth, Wtl, qkv, nullptr,
                                                     MROWS, 3072, 1024, 2048);
  pool_router2_kernel<<<dim3(BB * 25, 4), 256, 0, stream>>>(qkv, router);
  hipMemsetAsync(cnt, 0, 3200 * 4, stream);
  hipMemsetAsync(av, 0, (size_t)BB * HH * 25 * 64 * 4, stream);
  rg_fused_kernel<<<dim3(128, 17), 256, 0, stream>>>(qkv, router, rlog, rlogT, gateT, cnt, qlist);
  topk2_kernel<<<BB * HH * 25, 64, 0, stream>>>(rlog, topk, rowMax, rowRcp);
  agent_value7_kernel<<<dim3(128, 8), 256, 0, stream>>>(qkv, rlogT, rowMax, rowRcp, av);
  mixed_attn10_kernel<<<dim3(25, 128, 17), 64, 0, stream>>>(qkv, gateT, topk, av, cnt, qlist, attn);
  // out = attn @ Wproj + bproj : plain bf16 (32KB-LDS kernel -> 5 blocks/CU, no tail round)
  gemm_dbuf_plain_kernel<<<dim3(8, 65), 256, 0, stream>>>(attn, WpT, (float*)d_out, bproj,
                                                          MROWS, 1024, 1024);
}

// Round 17
// 504.851 us; speedup vs baseline: 1.1780x; 1.0706x over previous
//
#include <hip/hip_runtime.h>
#include <cstdint>

#define DEV static __device__ __forceinline__

typedef float f4v __attribute__((ext_vector_type(4)));
typedef short s8v __attribute__((ext_vector_type(8)));

// ---------- helpers ----------
DEV ushort f2bf(float f) {
  uint32_t u = __float_as_uint(f);
  uint32_t r = (u + 0x7FFFu + ((u >> 16) & 1u)) >> 16;   // RTNE
  return (ushort)r;
}
DEV float bf2f(ushort h) { return __uint_as_float(((uint32_t)h) << 16); }

DEV void lds_cp16(const void* g, void* l) {
  __builtin_amdgcn_global_load_lds((const __attribute__((address_space(1))) void*)g,
                                   (__attribute__((address_space(3))) void*)l, 16, 0, 0);
}

// ---------- constants ----------
#define BB 8
#define NN 1025
#define CC 1024
#define HH 16
#define DD 64
#define MM 25
#define KK 25
#define MROWS 8200          // B*N
#define SCALE 0.125f
#define GPITCH 28           // gateT row pitch (floats) -> 112B, 16B-aligned

// ---------- split x into bf16 hi/lo ----------
__global__ void split_x_kernel(const float* __restrict__ x, ushort* __restrict__ hi,
                               ushort* __restrict__ lo, int n4) {
  int i = blockIdx.x * 256 + threadIdx.x;
  if (i >= n4) return;
  float4 f = ((const float4*)x)[i];
  ushort4 h, l;
  h.x = f2bf(f.x); l.x = f2bf(f.x - bf2f(h.x));
  h.y = f2bf(f.y); l.y = f2bf(f.y - bf2f(h.y));
  h.z = f2bf(f.z); l.z = f2bf(f.z - bf2f(h.z));
  h.w = f2bf(f.w); l.w = f2bf(f.w - bf2f(h.w));
  ((ushort4*)hi)[i] = h;
  ((ushort4*)lo)[i] = l;
}

// ---------- transpose W[K][N] -> Wt[N][K] bf16 hi (+optional lo) ----------
__global__ void transpose_split_kernel(const float* __restrict__ W, ushort* __restrict__ hi,
                                       ushort* __restrict__ lo, int K, int N) {
  __shared__ float tile[32][33];
  int nb = blockIdx.x * 32, kb = blockIdx.y * 32;
  int tx = threadIdx.x, ty = threadIdx.y;      // 32x8
  for (int r = ty; r < 32; r += 8) tile[r][tx] = W[(size_t)(kb + r) * N + nb + tx];
  __syncthreads();
  for (int r = ty; r < 32; r += 8) {
    float f = tile[tx][r];                     // W[kb+tx][nb+r] -> Wt[nb+r][kb+tx]
    ushort h = f2bf(f);
    hi[(size_t)(nb + r) * K + kb + tx] = h;
    if (lo) lo[(size_t)(nb + r) * K + kb + tx] = f2bf(f - bf2f(h));
  }
}

// ---------- MFMA GEMM v3: 128x128 tile, double-buffered LDS, 2-phase pipeline (bf16x3) ----------
__global__ __launch_bounds__(256)
void gemm_dbuf_kernel(const ushort* __restrict__ Ah, const ushort* __restrict__ Al,
                      const ushort* __restrict__ Bh, const ushort* __restrict__ Bl,
                      float* __restrict__ C, const float* __restrict__ bias,
                      int M, int N, int K, int loN) {
  __shared__ ushort sm[32768];                 // 65536 B
  const int t = threadIdx.x;
  const int m0 = blockIdx.y * 128, n0 = blockIdx.x * 128;
  const bool three = (n0 < loN);
  const int lane = t & 63, wid = t >> 6;
  const int wy = wid >> 1, wx = wid & 1;       // 2x2 waves of 64x64
  const int lrow = lane & 15, lq = lane >> 4;
  const int slot = lq ^ ((lrow >> 1) & 3);     // fragment read swizzle

  f4v acc[4][4];
#pragma unroll
  for (int a = 0; a < 4; ++a)
#pragma unroll
    for (int b = 0; b < 4; ++b) acc[a][b] = (f4v)0.f;

  auto STAGE = [&](int p, int k0) {
    ushort* base = sm + p * 16384;
#pragma unroll
    for (int i = 0; i < 2; ++i) {
      int e = i * 256 + t;
      int row = e >> 2;
      int cgs = (e & 3) ^ ((e >> 3) & 3);      // staged k-group (XOR swizzle)
      int ebase = i * 256 + (t & 192);         // wave-uniform base
      size_t aoff = (size_t)min(m0 + row, M - 1) * K + k0 + cgs * 8;
      size_t boff = (size_t)(n0 + row) * K + k0 + cgs * 8;
      lds_cp16(Ah + aoff, base + (size_t)ebase * 8);
      lds_cp16(Bh + boff, base + 8192 + (size_t)ebase * 8);
      if (three) {
        lds_cp16(Al + aoff, base + 4096 + (size_t)ebase * 8);
        lds_cp16(Bl + boff, base + 12288 + (size_t)ebase * 8);
      }
    }
  };

  STAGE(0, 0);
  __syncthreads();
  int cur = 0;
  for (int k0 = 0; k0 < K; k0 += 32) {
    if (k0 + 32 < K) STAGE(cur ^ 1, k0 + 32);  // issue next tile (overlaps compute below)
    const ushort* sAh = sm + cur * 16384;
    const ushort* sAl = sAh + 4096;
    const ushort* sBh = sAh + 8192;
    const ushort* sBl = sAh + 12288;
    s8v fa[4], fb[4];
#pragma unroll
    for (int u = 0; u < 4; ++u) {
      fa[u] = *(const s8v*)(sAh + (((wy * 64 + u * 16 + lrow) * 4 + slot) * 8));
      fb[u] = *(const s8v*)(sBh + (((wx * 64 + u * 16 + lrow) * 4 + slot) * 8));
    }
#pragma unroll
    for (int mt = 0; mt < 4; ++mt)
#pragma unroll
      for (int nt = 0; nt < 4; ++nt)
        acc[mt][nt] = __builtin_amdgcn_mfma_f32_16x16x32_bf16(fa[mt], fb[nt], acc[mt][nt], 0, 0, 0);
    if (three) {
      s8v la[4], lb[4];
#pragma unroll
      for (int u = 0; u < 4; ++u) {
        la[u] = *(const s8v*)(sAl + (((wy * 64 + u * 16 + lrow) * 4 + slot) * 8));
        lb[u] = *(const s8v*)(sBl + (((wx * 64 + u * 16 + lrow) * 4 + slot) * 8));
      }
#pragma unroll
      for (int mt = 0; mt < 4; ++mt)
#pragma unroll
        for (int nt = 0; nt < 4; ++nt) {
          acc[mt][nt] = __builtin_amdgcn_mfma_f32_16x16x32_bf16(fa[mt], lb[nt], acc[mt][nt], 0, 0, 0);
          acc[mt][nt] = __builtin_amdgcn_mfma_f32_16x16x32_bf16(la[mt], fb[nt], acc[mt][nt], 0, 0, 0);
        }
    }
    __syncthreads();   // drains next-tile loads + fences read-before-overwrite
    cur ^= 1;
  }
  // epilogue: C/D layout col=lane&15, row=(lane>>4)*4+i  [m89/m91-verified]
#pragma unroll
  for (int mt = 0; mt < 4; ++mt) {
#pragma unroll
    for (int i = 0; i < 4; ++i) {
      int r = m0 + wy * 64 + mt * 16 + lq * 4 + i;
      if (r < M) {
#pragma unroll
        for (int nt = 0; nt < 4; ++nt) {
          int c = n0 + wx * 64 + nt * 16 + lrow;
          float v = acc[mt][nt][i];
          if (bias) v += bias[c];
          C[(size_t)r * N + c] = v;
        }
      }
    }
  }
}

// ---------- MFMA GEMM plain: 128x128 dbuf, NO hi/lo split -> 32KB LDS, 5 blocks/CU ----------
__global__ __launch_bounds__(256)
void gemm_dbuf_plain_kernel(const ushort* __restrict__ Ah, const ushort* __restrict__ Bh,
                            float* __restrict__ C, const float* __restrict__ bias,
                            int M, int N, int K) {
  __shared__ ushort sm[16384];                 // 32768 B: 2 bufs x (A 8KB | B 8KB)
  const int t = threadIdx.x;
  const int m0 = blockIdx.y * 128, n0 = blockIdx.x * 128;
  const int lane = t & 63, wid = t >> 6;
  const int wy = wid >> 1, wx = wid & 1;
  const int lrow = lane & 15, lq = lane >> 4;
  const int slot = lq ^ ((lrow >> 1) & 3);

  f4v acc[4][4];
#pragma unroll
  for (int a = 0; a < 4; ++a)
#pragma unroll
    for (int b = 0; b < 4; ++b) acc[a][b] = (f4v)0.f;

  auto STAGE = [&](int p, int k0) {
    ushort* base = sm + p * 8192;
#pragma unroll
    for (int i = 0; i < 2; ++i) {
      int e = i * 256 + t;
      int row = e >> 2;
      int cgs = (e & 3) ^ ((e >> 3) & 3);
      int ebase = i * 256 + (t & 192);
      size_t aoff = (size_t)min(m0 + row, M - 1) * K + k0 + cgs * 8;
      size_t boff = (size_t)(n0 + row) * K + k0 + cgs * 8;
      lds_cp16(Ah + aoff, base + (size_t)ebase * 8);
      lds_cp16(Bh + boff, base + 4096 + (size_t)ebase * 8);
    }
  };

  STAGE(0, 0);
  __syncthreads();
  int cur = 0;
  for (int k0 = 0; k0 < K; k0 += 32) {
    if (k0 + 32 < K) STAGE(cur ^ 1, k0 + 32);
    const ushort* sAh = sm + cur * 8192;
    const ushort* sBh = sAh + 4096;
    s8v fa[4], fb[4];
#pragma unroll
    for (int u = 0; u < 4; ++u) {
      fa[u] = *(const s8v*)(sAh + (((wy * 64 + u * 16 + lrow) * 4 + slot) * 8));
      fb[u] = *(const s8v*)(sBh + (((wx * 64 + u * 16 + lrow) * 4 + slot) * 8));
    }
#pragma unroll
    for (int mt = 0; mt < 4; ++mt)
#pragma unroll
      for (int nt = 0; nt < 4; ++nt)
        acc[mt][nt] = __builtin_amdgcn_mfma_f32_16x16x32_bf16(fa[mt], fb[nt], acc[mt][nt], 0, 0, 0);
    __syncthreads();
    cur ^= 1;
  }
#pragma unroll
  for (int mt = 0; mt < 4; ++mt) {
#pragma unroll
    for (int i = 0; i < 4; ++i) {
      int r = m0 + wy * 64 + mt * 16 + lq * 4 + i;
      if (r < M) {
#pragma unroll
        for (int nt = 0; nt < 4; ++nt) {
          int c = n0 + wx * 64 + nt * 16 + lrow;
          float v = acc[mt][nt][i];
          if (bias) v += bias[c];
          C[(size_t)r * N + c] = v;
        }
      }
    }
  }
}

// ---------- adaptive-pool router v2: grid (200, 4) x 256 threads -> all CUs busy ----------
__global__ __launch_bounds__(256)
void pool_router2_kernel(const float* __restrict__ qkv, float* __restrict__ router) {
  int bm = blockIdx.x;                 // b*25 + m
  int b = bm / 25, m = bm % 25;
  int p = m / 5, q = m % 5;
  int sp = (p * 32) / 5, ep = ((p + 1) * 32 + 4) / 5;
  int sq = (q * 32) / 5, eq = ((q + 1) * 32 + 4) / 5;
  float inv = 1.0f / (float)((ep - sp) * (eq - sq));
  int c = blockIdx.y * 256 + threadIdx.x;
  float s0 = 0.f;
  for (int hh = sp; hh < ep; ++hh)
    for (int ww = sq; ww < eq; ++ww)
      s0 += qkv[(size_t)(b * NN + hh * 32 + ww) * 3072 + c];
  router[(size_t)bm * 1024 + c] = s0 * inv;
}

// ---------- fused router logits + coalesced rlogT + gate transpose + argmax assign ----------
__global__ __launch_bounds__(256)
void rg_fused_kernel(const float* __restrict__ qkv, const float* __restrict__ router,
                     float* __restrict__ rlog, float* __restrict__ rlogT,
                     float* __restrict__ gateT,
                     int* __restrict__ cnt, int* __restrict__ qlist) {
  __shared__ float sQ[64 * 68];        // pitch 68 -> b128 reads conflict-free
  __shared__ float sK[64 * 68];
  __shared__ float sR[25 * 64];
  __shared__ float sG[64 * 27];        // gate tile, odd-ish pitch
  int bh = blockIdx.x, s = blockIdx.y;
  int b = bh >> 4, h = bh & 15;
  int base = s * 64, seglen = min(64, NN - base);
  int t = threadIdx.x;
  for (int e = t; e < 400; e += 256) {           // r: 25 rows x 16 float4
    int m = e >> 4, c4 = e & 15;
    *(float4*)&sR[m * 64 + c4 * 4] =
        *(const float4*)(router + (size_t)(b * 25 + m) * 1024 + h * 64 + c4 * 4);
  }
  for (int e = t; e < seglen * 16; e += 256) {   // q,k tiles coalesced
    int row = e >> 4, c4 = e & 15;
    const float* src = qkv + (size_t)(b * NN + base + row) * 3072 + h * 64 + c4 * 4;
    *(float4*)&sQ[row * 68 + c4 * 4] = *(const float4*)(src);
    *(float4*)&sK[row * 68 + c4 * 4] = *(const float4*)(src + 1024);
  }
  __syncthreads();
  int nl = t & 63, w = t >> 6;
  float kl[7];                         // k-logits, statically indexed (rule #20)
#pragma unroll
  for (int j = 0; j < 7; ++j) kl[j] = 0.f;
  if (nl < seglen) {
    float4 rowreg[16];
#pragma unroll
    for (int c4 = 0; c4 < 16; ++c4) rowreg[c4] = *(const float4*)&sQ[nl * 68 + c4 * 4];
    for (int m = w; m < 25; m += 4) {
      const float* rp = &sR[m * 64];
      float a = 0.f;
#pragma unroll
      for (int c4 = 0; c4 < 16; ++c4) {
        float4 r4 = *(const float4*)(rp + c4 * 4);        // broadcast within wave
        a += rowreg[c4].x * r4.x + rowreg[c4].y * r4.y +
             rowreg[c4].z * r4.z + rowreg[c4].w * r4.w;
      }
      sG[nl * 27 + m] = a;
    }
#pragma unroll
    for (int c4 = 0; c4 < 16; ++c4) rowreg[c4] = *(const float4*)&sK[nl * 68 + c4 * 4];
#pragma unroll
    for (int j = 0; j < 7; ++j) {
      int m = w + 4 * j;
      if (m < 25) {
        const float* rp = &sR[m * 64];
        float a = 0.f;
#pragma unroll
        for (int c4 = 0; c4 < 16; ++c4) {
          float4 r4 = *(const float4*)(rp + c4 * 4);
          a += rowreg[c4].x * r4.x + rowreg[c4].y * r4.y +
               rowreg[c4].z * r4.z + rowreg[c4].w * r4.w;
        }
        rlog[(size_t)(bh * 25 + m) * NN + base + nl] = a;   // coalesced per m
        kl[j] = a;
      }
    }
  }
  __syncthreads();                     // A: all sQ reads complete -> safe to reuse
  float* sT = sQ;                      // [64][26] scratch for rlogT transpose
  if (nl < seglen) {
#pragma unroll
    for (int j = 0; j < 7; ++j) {
      int m = w + 4 * j;
      if (m < 25) sT[nl * 26 + m] = kl[j];
    }
  }
  __syncthreads();                     // B: sT complete
  {
    // [seglen x 25] target region is exactly linear -> fully coalesced dwords
    float* dst = rlogT + (size_t)(bh * NN + base) * 25;
    for (int i = t; i < seglen * 25; i += 256) {
      int row = i / 25, m = i - row * 25;
      dst[i] = sT[row * 26 + m];
    }
  }
  if (t < seglen) {
    const float* gp = &sG[t * 27];
    float* gout = gateT + ((size_t)bh * NN + base + t) * GPITCH;
    float best = -INFINITY; int bi = 0;
#pragma unroll
    for (int m = 0; m < 25; ++m) {
      float v = gp[m];
      gout[m] = v;
      if (v > best) { best = v; bi = m; }      // strict > : first-max, matches jnp.argmax
    }
    int pos = atomicAdd(&cnt[bh * 25 + bi], 1);
    qlist[(bh * 25 + bi) * NN + pos] = base + t;
  }
}

// ---------- top-25 of each rlog row + softmax row stats (one wave per row) ----------
__global__ void topk2_kernel(const float* __restrict__ rlog, int* __restrict__ topk,
                             float* __restrict__ rowMax, float* __restrict__ rowRcp) {
  int row = blockIdx.x;                // (b*16+h)*25+m
  int l = threadIdx.x;                 // 0..63
  const float* src = rlog + (size_t)row * NN;
  float vals[17];
#pragma unroll
  for (int i = 0; i < 17; ++i) {
    int n = l + i * 64;
    vals[i] = (n < NN) ? src[n] : -INFINITY;
  }
  {
    float mx = vals[0];
#pragma unroll
    for (int i = 1; i < 17; ++i) mx = fmaxf(mx, vals[i]);
#pragma unroll
    for (int off = 32; off; off >>= 1) mx = fmaxf(mx, __shfl_xor(mx, off));
    float mxs = mx * SCALE;
    float sum = 0.f;
#pragma unroll
    for (int i = 0; i < 17; ++i) sum += __expf(vals[i] * SCALE - mxs);  // exp(-inf)=0
#pragma unroll
    for (int off = 32; off; off >>= 1) sum += __shfl_xor(sum, off);
    if (l == 0) { rowMax[row] = mxs; rowRcp[row] = 1.0f / sum; }
  }
  int* out = topk + row * 25;
  for (int r = 0; r < 25; ++r) {
    float best = vals[0]; int bi = 0;
#pragma unroll
    for (int i = 1; i < 17; ++i)
      if (vals[i] > best) { best = vals[i]; bi = i; }
    int bn = l + bi * 64;
#pragma unroll
    for (int off = 32; off; off >>= 1) {
      float ov = __shfl_down(best, off);
      int on = __shfl_down(bn, off);
      if (ov > best || (ov == best && on < bn)) { best = ov; bn = on; }
    }
    bn = __shfl(bn, 0);
    if (l == 0) out[r] = bn;
    if ((bn & 63) == l) vals[bn >> 6] = -INFINITY;
  }
}

// ---------- agent value v7: V read ONCE; per-n contiguous rlogT weights; LDS wave-reduce ----------
__global__ __launch_bounds__(256)
void agent_value7_kernel(const float* __restrict__ qkv, const float* __restrict__ rlogT,
                         const float* __restrict__ rowMax, const float* __restrict__ rowRcp,
                         float* __restrict__ av) {
  __shared__ float red[4][25][64];     // 25.6 KB
  int bh = blockIdx.x, sl = blockIdx.y;
  int w = threadIdx.x >> 6, l = threadIdx.x & 63;
  int b = bh >> 4, h = bh & 15;
  int n0 = (sl * 4 + w) * 32;
  int n1 = (sl == 7 && w == 3) ? NN : n0 + 32;
  float mxs[25];
#pragma unroll
  for (int m = 0; m < 25; ++m) mxs[m] = rowMax[bh * 25 + m];
  const float* vb = qkv + (size_t)b * NN * 3072 + 2048 + h * 64 + l;
  const float* rT = rlogT + (size_t)bh * NN * 25;
  float acc[25];
#pragma unroll
  for (int m = 0; m < 25; ++m) acc[m] = 0.f;
  for (int n = n0; n < n1; ++n) {
    float v = vb[(size_t)n * 3072];              // coalesced 256B row, read once
    const float* r = rT + (size_t)n * 25;        // wave-uniform contiguous 25 floats
#pragma unroll
    for (int m = 0; m < 25; ++m)
      acc[m] += __expf(r[m] * SCALE - mxs[m]) * v;
  }
#pragma unroll
  for (int m = 0; m < 25; ++m) red[w][m][l] = acc[m];
  __syncthreads();
  for (int i = threadIdx.x; i < 1600; i += 256) {
    int m = i >> 6, ll = i & 63;
    float s = red[0][m][ll] + red[1][m][ll] + red[2][m][ll] + red[3][m][ll];
    atomicAdd(&av[((size_t)bh * 25 + m) * 64 + ll], s * rowRcp[bh * 25 + m]);
  }
}

// ---------- mixed attention v10: LDS-staged Ksel/Vsel/AV + early-issue q/gate ----------
__global__ __launch_bounds__(64)
void mixed_attn10_kernel(const float* __restrict__ qkv, const float* __restrict__ gateT,
                         const int* __restrict__ topk, const float* __restrict__ av,
                         const int* __restrict__ cnt, const int* __restrict__ qlist,
                         ushort* __restrict__ attn) {
  __shared__ float sK[25 * 64];
  __shared__ float sV[25 * 64];
  __shared__ float sA[25 * 64];
  int e = blockIdx.x, bh = blockIdx.y;
  int c0 = blockIdx.z * 64;
  int ce = cnt[bh * 25 + e];
  if (c0 >= ce) return;
  int b = bh >> 4, h = bh & 15;
  int l = threadIdx.x;                 // 64 threads = 1 wave
  const int* tkp = topk + bh * 625 + e * 25;
  const float* qb = qkv + (size_t)b * NN * 3072 + h * 64;
  const int* ql = qlist + (bh * 25 + e) * NN;

  // ---- early-issue per-lane loads: q row (scattered) + gate row; in flight during staging ----
  int qi = c0 + l;
  bool act = qi < ce;
  int n = ql[act ? qi : c0];
  const float* qr = qb + (size_t)n * 3072;
  float4 q4[16];
#pragma unroll
  for (int d4 = 0; d4 < 16; ++d4) q4[d4] = *(const float4*)(qr + d4 * 4);
  const float* gr = gateT + ((size_t)bh * NN + n) * GPITCH;
  float4 gv0 = *(const float4*)(gr);
  float4 gv1 = *(const float4*)(gr + 4);
  float4 gv2 = *(const float4*)(gr + 8);
  float4 gv3 = *(const float4*)(gr + 12);
  float4 gv4 = *(const float4*)(gr + 16);
  float4 gv5 = *(const float4*)(gr + 20);
  float g24 = gr[24];

  // ---- cooperative stage (coalesced): 25 K rows, 25 V rows, 25 AV rows ----
  for (int i = l; i < 400; i += 64) {
    int row = i >> 4, c4 = (i & 15) * 4;
    const float* src = qb + (size_t)tkp[row] * 3072 + 1024 + c4;
    *(float4*)&sK[row * 64 + c4] = *(const float4*)(src);
    *(float4*)&sV[row * 64 + c4] = *(const float4*)(src + 1024);
  }
  {
    const float* avb = av + (size_t)bh * 25 * 64;
    for (int i = l; i < 400; i += 64)
      *(float4*)&sA[i * 4] = *(const float4*)(avb + i * 4);
  }
  __syncthreads();   // drains staging AND the early-issued q4/gate loads together

  // ---- pass 1: all 50 logits into registers ----
  float myW[50];
  myW[0] = gv0.x; myW[1] = gv0.y; myW[2] = gv0.z; myW[3] = gv0.w;
  myW[4] = gv1.x; myW[5] = gv1.y; myW[6] = gv1.z; myW[7] = gv1.w;
  myW[8] = gv2.x; myW[9] = gv2.y; myW[10] = gv2.z; myW[11] = gv2.w;
  myW[12] = gv3.x; myW[13] = gv3.y; myW[14] = gv3.z; myW[15] = gv3.w;
  myW[16] = gv4.x; myW[17] = gv4.y; myW[18] = gv4.z; myW[19] = gv4.w;
  myW[20] = gv5.x; myW[21] = gv5.y; myW[22] = gv5.z; myW[23] = gv5.w;
  myW[24] = g24;
#pragma unroll
  for (int m = 0; m < 25; ++m) myW[m] *= SCALE;
#pragma unroll
  for (int j = 0; j < 25; ++j) {
    const float4* kr = (const float4*)&sK[j * 64];
    float a = 0.f;
#pragma unroll
    for (int d4 = 0; d4 < 16; ++d4) {
      float4 k4 = kr[d4];
      a += q4[d4].x * k4.x + q4[d4].y * k4.y + q4[d4].z * k4.z + q4[d4].w * k4.w;
    }
    myW[25 + j] = a * SCALE;
  }
  // ---- softmax over 50 (unnormalized exps; normalize at store) ----
  float mx = myW[0];
#pragma unroll
  for (int i = 1; i < 50; ++i) mx = fmaxf(mx, myW[i]);
  float tot = 0.f;
#pragma unroll
  for (int i = 0; i < 50; ++i) { float w = __expf(myW[i] - mx); myW[i] = w; tot += w; }
  float rcp = 1.0f / tot;

  // ---- pass 2: output accumulate from LDS ----
  float4 o[16];
#pragma unroll
  for (int d4 = 0; d4 < 16; ++d4) o[d4] = make_float4(0.f, 0.f, 0.f, 0.f);
#pragma unroll
  for (int m = 0; m < 25; ++m) {
    const float4* src = (const float4*)&sA[m * 64];
    float wv = myW[m];
#pragma unroll
    for (int d4 = 0; d4 < 16; ++d4) {
      float4 a4 = src[d4];
      o[d4].x += wv * a4.x; o[d4].y += wv * a4.y;
      o[d4].z += wv * a4.z; o[d4].w += wv * a4.w;
    }
  }
#pragma unroll
  for (int j = 0; j < 25; ++j) {
    const float4* src = (const float4*)&sV[j * 64];
    float wv = myW[25 + j];
#pragma unroll
    for (int d4 = 0; d4 < 16; ++d4) {
      float4 a4 = src[d4];
      o[d4].x += wv * a4.x; o[d4].y += wv * a4.y;
      o[d4].z += wv * a4.z; o[d4].w += wv * a4.w;
    }
  }
  if (act) {
    ushort* orow = attn + (size_t)(b * NN + n) * 1024 + h * 64;
#pragma unroll
    for (int d4 = 0; d4 < 16; ++d4) {
      ushort4 u;
      u.x = f2bf(o[d4].x * rcp); u.y = f2bf(o[d4].y * rcp);
      u.z = f2bf(o[d4].z * rcp); u.w = f2bf(o[d4].w * rcp);
      *(ushort4*)(orow + d4 * 4) = u;
    }
  }
}

// ---------- launch ----------
extern "C" void kernel_launch(void* const* d_in, const int* in_sizes, int n_in,
                              void* d_out, int out_size, void* d_ws, size_t ws_size,
                              hipStream_t stream) {
  const float* x = (const float*)d_in[0];
  const float* Wqkv = (const float*)d_in[1];
  const float* Wproj = (const float*)d_in[2];
  const float* bproj = (const float*)d_in[3];

  char* ws = (char*)d_ws;
  size_t off = 0;
  float* qkv = (float*)(ws + off);      off += (size_t)MROWS * 3072 * 4;    // 100,761,600
  ushort* xh = (ushort*)(ws + off);     off += (size_t)MROWS * 1024 * 2;    // 16,793,600
  ushort* xl = (ushort*)(ws + off);     off += (size_t)MROWS * 1024 * 2;
  ushort* Wth = (ushort*)(ws + off);    off += (size_t)3072 * 1024 * 2;     // 6,291,456
  ushort* Wtl = (ushort*)(ws + off);    off += (size_t)3072 * 1024 * 2;
  ushort* WpT = (ushort*)(ws + off);    off += (size_t)1024 * 1024 * 2;     // 2,097,152
  float* router = (float*)(ws + off);   off += (size_t)BB * 25 * 1024 * 4;  // 819,200
  float* rlog = (float*)(ws + off);     off += (size_t)BB * HH * 25 * NN * 4; // 13,120,000
  float* rlogT = (float*)(ws + off);    off += (size_t)BB * HH * NN * 25 * 4; // 13,120,000
  int* topk = (int*)(ws + off);         off += (size_t)BB * HH * 25 * 25 * 4; // 320,000
  float* av = (float*)(ws + off);       off += (size_t)BB * HH * 25 * 64 * 4; // 819,200
  ushort* attn = (ushort*)(ws + off);   off += (size_t)MROWS * 1024 * 2;
  float* rowMax = (float*)(ws + off);   off += (size_t)BB * HH * 25 * 4;    // 12,800
  float* rowRcp = (float*)(ws + off);   off += (size_t)BB * HH * 25 * 4;

  // xh/xl are dead after the qkv GEMM -> reuse for routing metadata
  float* gateT = (float*)xh;                               // 128*1025*28*4 = 14,694,400 B
  int* cnt = (int*)((char*)xh + 14694400);                 // 12,800 B (total <= 16,793,600)
  int* qlist = (int*)xl;                                   // 13,120,000 B

  split_x_kernel<<<8200, 256, 0, stream>>>(x, xh, xl, 2099200);
  transpose_split_kernel<<<dim3(96, 32), dim3(32, 8), 0, stream>>>(Wqkv, Wth, Wtl, 1024, 3072);
  transpose_split_kernel<<<dim3(32, 32), dim3(32, 8), 0, stream>>>(Wproj, WpT, nullptr, 1024, 1024);
  // qkv = x @ Wqkv : bf16x3 for q,k columns (<2048), plain bf16 for v columns
  gemm_dbuf_kernel<<<dim3(24, 65), 256, 0, stream>>>(xh, xl, Wth, Wtl, qkv, nullptr,
                                                     MROWS, 3072, 1024, 2048);
  pool_router2_kernel<<<dim3(BB * 25, 4), 256, 0, stream>>>(qkv, router);
  hipMemsetAsync(cnt, 0, 3200 * 4, stream);
  hipMemsetAsync(av, 0, (size_t)BB * HH * 25 * 64 * 4, stream);
  rg_fused_kernel<<<dim3(128, 17), 256, 0, stream>>>(qkv, router, rlog, rlogT, gateT, cnt, qlist);
  topk2_kernel<<<BB * HH * 25, 64, 0, stream>>>(rlog, topk, rowMax, rowRcp);
  agent_value7_kernel<<<dim3(128, 8), 256, 0, stream>>>(qkv, rlogT, rowMax, rowRcp, av);
  mixed_attn10_kernel<<<dim3(25, 128, 17), 64, 0, stream>>>(qkv, gateT, topk, av, cnt, qlist, attn);
  // out = attn @ Wproj + bproj : plain bf16 (32KB-LDS kernel -> 5 blocks/CU, no tail round)
  gemm_dbuf_plain_kernel<<<dim3(8, 65), 256, 0, stream>>>(attn, WpT, (float*)d_out, bproj,
                                                          MROWS, 1024, 1024);
}